// Round 1
// baseline (15948.471 us; speedup 1.0000x reference)
//
#include <hip/hip_runtime.h>
#include <math.h>

// ---- problem constants ----
constexpr int cB   = 2;
constexpr int cS   = 1024;
constexpr int cD   = 2048;
constexpr int cH   = 8;
constexpr int cHD  = 256;
constexpr int cKV  = 4;
constexpr int cGHD = 512;
constexpr int cGKV = 4;
constexpr int cROT = 128;
constexpr int cF   = 8192;
constexpr int cV   = 32000;
constexpr int cWIN = 512;
constexpr int cM   = cB * cS;   // 2048 token rows
constexpr float cEPS = 1e-6f;

// ---------------------------------------------------------------------------
// embed lookup * sqrt(D)
// ---------------------------------------------------------------------------
__global__ void embed_kernel(const int* __restrict__ tok,
                             const float* __restrict__ emb,
                             float* __restrict__ out) {
    const int row = blockIdx.x;              // b*S + s
    const int t = tok[row];
    const float* e = emb + (size_t)t * cD;
    float* o = out + (size_t)row * cD;
    const float sc = sqrtf((float)cD);
    for (int d = threadIdx.x; d < cD; d += blockDim.x) o[d] = e[d] * sc;
}

// ---------------------------------------------------------------------------
// row RMS norm: out = x * rsqrt(mean(x^2)+eps) * (w or 1)
// one block per row; 256 threads
// ---------------------------------------------------------------------------
__global__ void rms_kernel(const float* __restrict__ x,
                           const float* __restrict__ w,
                           float* __restrict__ out, int dim) {
    const int row = blockIdx.x;
    const float* xr = x + (size_t)row * dim;
    float* orow = out + (size_t)row * dim;
    float ss = 0.f;
    for (int d = threadIdx.x; d < dim; d += blockDim.x) { float v = xr[d]; ss += v * v; }
    for (int o = 32; o >= 1; o >>= 1) ss += __shfl_xor(ss, o);
    __shared__ float rb[8];
    if ((threadIdx.x & 63) == 0) rb[threadIdx.x >> 6] = ss;
    __syncthreads();
    ss = rb[0] + rb[1] + rb[2] + rb[3];
    const float r = rsqrtf(ss / dim + cEPS);
    for (int d = threadIdx.x; d < dim; d += blockDim.x)
        orow[d] = xr[d] * r * (w ? w[d] : 1.f);
}

// out = (res + x * rsqrt(mean(x^2)+eps) * w) * (scal or 1)   (out may alias res)
__global__ void rms_add_kernel(const float* __restrict__ res,
                               const float* __restrict__ x,
                               const float* __restrict__ w,
                               const float* __restrict__ scal,
                               float* __restrict__ out, int dim) {
    const int row = blockIdx.x;
    const float* xr = x + (size_t)row * dim;
    const float* rr = res + (size_t)row * dim;
    float* orow = out + (size_t)row * dim;
    float ss = 0.f;
    for (int d = threadIdx.x; d < dim; d += blockDim.x) { float v = xr[d]; ss += v * v; }
    for (int o = 32; o >= 1; o >>= 1) ss += __shfl_xor(ss, o);
    __shared__ float rb[8];
    if ((threadIdx.x & 63) == 0) rb[threadIdx.x >> 6] = ss;
    __syncthreads();
    ss = rb[0] + rb[1] + rb[2] + rb[3];
    const float r = rsqrtf(ss / dim + cEPS);
    const float sc = scal ? *scal : 1.f;
    for (int d = threadIdx.x; d < dim; d += blockDim.x)
        orow[d] = (rr[d] + xr[d] * r * w[d]) * sc;
}

// ---------------------------------------------------------------------------
// RoPE in place on first `rot` dims of each head row.
// grid = B*S*NH blocks, row = (b*S+s)*NH + h
// ---------------------------------------------------------------------------
__global__ void rope_kernel(float* __restrict__ x, int NH, int HDIM, int rot, float theta) {
    const int row = blockIdx.x;
    const int s = (row / NH) % cS;
    float* xr = x + (size_t)row * HDIM;
    const int half = rot >> 1;
    for (int i = threadIdx.x; i < half; i += blockDim.x) {
        const float inv = powf(theta, -(2.f * i) / (float)rot);
        const float ang = (float)s * inv;
        const float c = cosf(ang), sn = sinf(ang);
        const float x1 = xr[2 * i], x2 = xr[2 * i + 1];
        xr[2 * i]     = x1 * c - x2 * sn;
        xr[2 * i + 1] = x1 * sn + x2 * c;
    }
}

// ---------------------------------------------------------------------------
// fp32 GEMM, C[M,N] = A[M,K] @ B[K,N]  (BT: B stored [N,K], i.e. C = A @ B^T)
// 64x64 tile, BK=16, 256 threads, 4x4 per thread. All dims multiples of 64/16.
// ---------------------------------------------------------------------------
template<bool BT>
__global__ __launch_bounds__(256) void gemm64(const float* __restrict__ A,
                                              const float* __restrict__ Bm,
                                              float* __restrict__ C,
                                              int M, int N, int K) {
    __shared__ float As[16][64];
    __shared__ float Bs[16][64];
    const int bm = blockIdx.y * 64;
    const int bn = blockIdx.x * 64;
    const int tid = threadIdx.x;
    const int tx = tid & 15, ty = tid >> 4;
    float acc[4][4] = {};
    for (int k0 = 0; k0 < K; k0 += 16) {
        {   // A tile: rows bm..bm+63, k k0..k0+15, transposed into As[kk][m]
            const int m = tid >> 2;
            const int kk = (tid & 3) * 4;
            const float4 a4 = *reinterpret_cast<const float4*>(&A[(size_t)(bm + m) * K + k0 + kk]);
            As[kk + 0][m] = a4.x; As[kk + 1][m] = a4.y;
            As[kk + 2][m] = a4.z; As[kk + 3][m] = a4.w;
        }
        if (!BT) {
            const int kk = tid >> 4;
            const int n = (tid & 15) * 4;
            const float4 b4 = *reinterpret_cast<const float4*>(&Bm[(size_t)(k0 + kk) * N + bn + n]);
            Bs[kk][n + 0] = b4.x; Bs[kk][n + 1] = b4.y;
            Bs[kk][n + 2] = b4.z; Bs[kk][n + 3] = b4.w;
        } else {
            const int n = tid >> 2;
            const int kk = (tid & 3) * 4;
            const float4 b4 = *reinterpret_cast<const float4*>(&Bm[(size_t)(bn + n) * K + k0 + kk]);
            Bs[kk + 0][n] = b4.x; Bs[kk + 1][n] = b4.y;
            Bs[kk + 2][n] = b4.z; Bs[kk + 3][n] = b4.w;
        }
        __syncthreads();
#pragma unroll
        for (int kk = 0; kk < 16; ++kk) {
            float a[4], b[4];
#pragma unroll
            for (int i = 0; i < 4; ++i) a[i] = As[kk][ty * 4 + i];
#pragma unroll
            for (int j = 0; j < 4; ++j) b[j] = Bs[kk][tx * 4 + j];
#pragma unroll
            for (int i = 0; i < 4; ++i)
#pragma unroll
                for (int j = 0; j < 4; ++j) acc[i][j] += a[i] * b[j];
        }
        __syncthreads();
    }
#pragma unroll
    for (int i = 0; i < 4; ++i)
#pragma unroll
        for (int j = 0; j < 4; ++j)
            C[(size_t)(bm + ty * 4 + i) * N + bn + tx * 4 + j] = acc[i][j];
}

// ---------------------------------------------------------------------------
// attention: one block per (q, h, b). Q,K,V in [B,S,heads,HDIM] layout.
// win>0 -> sliding window; win==0 -> full causal. No score scaling (per ref).
// ---------------------------------------------------------------------------
template<int HDIM>
__global__ __launch_bounds__(256) void attn_kernel(const float* __restrict__ Q,
                                                   const float* __restrict__ K,
                                                   const float* __restrict__ V,
                                                   float* __restrict__ O,
                                                   const int* __restrict__ tlen,
                                                   int KVH, int win) {
    const int q = blockIdx.x, h = blockIdx.y, b = blockIdx.z;
    const int kh = h / (cH / KVH);
    __shared__ float qs[HDIM];
    __shared__ float sc[cS];
    __shared__ float rb[8];
    const int tid = threadIdx.x;
    const int lane = tid & 63, wid = tid >> 6;

    const float* qrow = Q + (((size_t)b * cS + q) * cH + h) * HDIM;
    for (int d = tid; d < HDIM; d += 256) qs[d] = qrow[d];
    __syncthreads();

    const int tl = tlen[b];
    const int kmax = min(q, tl - 1);
    const int kmin = (win > 0) ? max(0, q - win + 1) : 0;
    const int n = kmax - kmin + 1;

    // scores: one wave per key
    for (int k = kmin + wid; k <= kmax; k += 4) {
        const float* kr = K + (((size_t)b * cS + k) * KVH + kh) * HDIM;
        float p = 0.f;
#pragma unroll
        for (int d = lane; d < HDIM; d += 64) p += qs[d] * kr[d];
        for (int o = 32; o >= 1; o >>= 1) p += __shfl_xor(p, o);
        if (lane == 0) sc[k - kmin] = p;
    }
    __syncthreads();

    // softmax over sc[0..n)
    float m = -1e30f;
    for (int i = tid; i < n; i += 256) m = fmaxf(m, sc[i]);
    for (int o = 32; o >= 1; o >>= 1) m = fmaxf(m, __shfl_xor(m, o));
    if (lane == 0) rb[wid] = m;
    __syncthreads();
    m = fmaxf(fmaxf(rb[0], rb[1]), fmaxf(rb[2], rb[3]));

    float ssum = 0.f;
    for (int i = tid; i < n; i += 256) { float e = expf(sc[i] - m); sc[i] = e; ssum += e; }
    for (int o = 32; o >= 1; o >>= 1) ssum += __shfl_xor(ssum, o);
    if (lane == 0) rb[4 + wid] = ssum;
    __syncthreads();
    ssum = rb[4] + rb[5] + rb[6] + rb[7];
    const float inv = 1.f / ssum;

    // PV
    for (int d = tid; d < HDIM; d += 256) {
        float acc = 0.f;
        for (int k = kmin; k <= kmax; ++k)
            acc += sc[k - kmin] * V[(((size_t)b * cS + k) * KVH + kh) * HDIM + d];
        O[(((size_t)b * cS + q) * cH + h) * HDIM + d] = acc * inv;
    }
}

// ---------------------------------------------------------------------------
// gated FFN elementwise: g = gelu_tanh(g) * u   (float4 vectorized)
// ---------------------------------------------------------------------------
__global__ void gelumul_kernel(float* __restrict__ g, const float* __restrict__ u, int n4) {
    const int i = blockIdx.x * blockDim.x + threadIdx.x;
    if (i >= n4) return;
    float4 gv = reinterpret_cast<float4*>(g)[i];
    const float4 uv = reinterpret_cast<const float4*>(u)[i];
    auto gelu = [](float v) {
        const float t = tanhf(0.7978845608028654f * (v + 0.044715f * v * v * v));
        return 0.5f * v * (1.f + t);
    };
    gv.x = gelu(gv.x) * uv.x;
    gv.y = gelu(gv.y) * uv.y;
    gv.z = gelu(gv.z) * uv.z;
    gv.w = gelu(gv.w) * uv.w;
    reinterpret_cast<float4*>(g)[i] = gv;
}

// ---------------------------------------------------------------------------
extern "C" void kernel_launch(void* const* d_in, const int* in_sizes, int n_in,
                              void* d_out, int out_size, void* d_ws, size_t ws_size,
                              hipStream_t stream) {
    (void)in_sizes; (void)n_in; (void)out_size; (void)ws_size;
    const int*   tokens = (const int*)  d_in[0];
    const int*   tlen   = (const int*)  d_in[1];
    const float* embed  = (const float*)d_in[2];
    const float* norm_w = (const float*)d_in[3];
    const float* s_wq   = (const float*)d_in[4];
    const float* s_wk   = (const float*)d_in[5];
    const float* s_wv   = (const float*)d_in[6];
    const float* s_wo   = (const float*)d_in[7];
    const float* s_qn   = (const float*)d_in[8];
    const float* s_kn   = (const float*)d_in[9];
    const float* s_wg   = (const float*)d_in[10];
    const float* s_wu   = (const float*)d_in[11];
    const float* s_wd   = (const float*)d_in[12];
    const float* s_ln1  = (const float*)d_in[13];
    const float* s_ln2  = (const float*)d_in[14];
    const float* s_ln3  = (const float*)d_in[15];
    const float* s_ln4  = (const float*)d_in[16];
    const float* s_scal = (const float*)d_in[17];
    const float* g_wq   = (const float*)d_in[18];
    const float* g_wk   = (const float*)d_in[19];
    const float* g_wo   = (const float*)d_in[20];
    const float* g_qn   = (const float*)d_in[21];
    const float* g_kn   = (const float*)d_in[22];
    const float* g_wg   = (const float*)d_in[23];
    const float* g_wu   = (const float*)d_in[24];
    const float* g_wd   = (const float*)d_in[25];
    const float* g_ln1  = (const float*)d_in[26];
    const float* g_ln2  = (const float*)d_in[27];
    const float* g_ln3  = (const float*)d_in[28];
    const float* g_ln4  = (const float*)d_in[29];
    const float* g_scal = (const float*)d_in[30];

    // workspace layout (needs 160 MB):
    //   [0,16)   x   residual
    //   [16,32)  hn  normed rows / ffn-out reuse
    //   [32,64)  qb  (32MB, block-g q is 2048x4096)      -- FFN t0 = [32,96)
    //   [64,80)  kb  (16MB)                              -- oproj reuse
    //   [80,96)  vb  (16MB)
    //   [96,160) ob  (32MB attn out)                     -- FFN t1 = [96,160)
    char* w8 = (char*)d_ws;
    float* x  = (float*)(w8);
    float* hn = (float*)(w8 + (size_t)16  * 1024 * 1024);
    float* qb = (float*)(w8 + (size_t)32  * 1024 * 1024);
    float* kb = (float*)(w8 + (size_t)64  * 1024 * 1024);
    float* vb = (float*)(w8 + (size_t)80  * 1024 * 1024);
    float* ob = (float*)(w8 + (size_t)96  * 1024 * 1024);
    float* t0 = qb;   // 64MB span [32,96)
    float* t1 = ob;   // 64MB span [96,160)

    auto gemmNN = [&](const float* A, const float* Bm, float* C, int M, int N, int K) {
        gemm64<false><<<dim3(N / 64, M / 64), 256, 0, stream>>>(A, Bm, C, M, N, K);
    };

    // ---- embed ----
    embed_kernel<<<cM, 256, 0, stream>>>(tokens, embed, x);

    // ================= block 1: sliding-window =================
    rms_kernel<<<cM, 256, 0, stream>>>(x, s_ln1, hn, cD);
    gemmNN(hn, s_wq, qb, cM, cH * cHD, cD);
    gemmNN(hn, s_wk, kb, cM, cKV * cHD, cD);
    gemmNN(hn, s_wv, vb, cM, cKV * cHD, cD);
    rms_kernel<<<cM * cKV, 256, 0, stream>>>(vb, nullptr, vb, cHD);      // xv = rms_ns(h@wv)
    rms_kernel<<<cM * cH, 256, 0, stream>>>(qb, s_qn, qb, cHD);
    rms_kernel<<<cM * cKV, 256, 0, stream>>>(kb, s_kn, kb, cHD);
    rope_kernel<<<cM * cH, 128, 0, stream>>>(qb, cH, cHD, cHD, 10000.f);
    rope_kernel<<<cM * cKV, 128, 0, stream>>>(kb, cKV, cHD, cHD, 10000.f);
    attn_kernel<cHD><<<dim3(cS, cH, cB), 256, 0, stream>>>(qb, kb, vb, ob, tlen, cKV, cWIN);
    gemmNN(ob, s_wo, kb, cM, cD, cH * cHD);                              // oproj -> kb
    rms_add_kernel<<<cM, 256, 0, stream>>>(x, kb, s_ln2, nullptr, x, cD);
    rms_kernel<<<cM, 256, 0, stream>>>(x, s_ln3, hn, cD);
    gemmNN(hn, s_wg, t0, cM, cF, cD);
    gemmNN(hn, s_wu, t1, cM, cF, cD);
    gelumul_kernel<<<(cM * cF / 4 + 255) / 256, 256, 0, stream>>>(t0, t1, cM * cF / 4);
    gemmNN(t0, s_wd, hn, cM, cD, cF);                                    // ffn out -> hn
    rms_add_kernel<<<cM, 256, 0, stream>>>(x, hn, s_ln4, s_scal, x, cD);

    // ================= block 2: global =================
    rms_kernel<<<cM, 256, 0, stream>>>(x, g_ln1, hn, cD);
    gemmNN(hn, g_wq, qb, cM, cH * cGHD, cD);
    gemmNN(hn, g_wk, kb, cM, cGKV * cGHD, cD);
    rms_kernel<<<cM * cGKV, 256, 0, stream>>>(kb, nullptr, vb, cGHD);    // xv = rms_ns(raw xk)
    rms_kernel<<<cM * cH, 256, 0, stream>>>(qb, g_qn, qb, cGHD);
    rms_kernel<<<cM * cGKV, 256, 0, stream>>>(kb, g_kn, kb, cGHD);
    rope_kernel<<<cM * cH, 64, 0, stream>>>(qb, cH, cGHD, cROT, 1000000.f);
    rope_kernel<<<cM * cGKV, 64, 0, stream>>>(kb, cGKV, cGHD, cROT, 1000000.f);
    attn_kernel<cGHD><<<dim3(cS, cH, cB), 256, 0, stream>>>(qb, kb, vb, ob, tlen, cGKV, 0);
    gemmNN(ob, g_wo, kb, cM, cD, cH * cGHD);                             // oproj -> kb
    rms_add_kernel<<<cM, 256, 0, stream>>>(x, kb, g_ln2, nullptr, x, cD);
    rms_kernel<<<cM, 256, 0, stream>>>(x, g_ln3, hn, cD);
    gemmNN(hn, g_wg, t0, cM, cF, cD);
    gemmNN(hn, g_wu, t1, cM, cF, cD);
    gelumul_kernel<<<(cM * cF / 4 + 255) / 256, 256, 0, stream>>>(t0, t1, cM * cF / 4);
    gemmNN(t0, g_wd, hn, cM, cD, cF);
    rms_add_kernel<<<cM, 256, 0, stream>>>(x, hn, g_ln4, g_scal, x, cD);

    // ================= final norm + logits =================
    rms_kernel<<<cM, 256, 0, stream>>>(x, norm_w, hn, cD);
    gemm64<true><<<dim3(cV / 64, cM / 64), 256, 0, stream>>>(hn, embed, (float*)d_out, cM, cV, cD);
}

// Round 3
// 7763.763 us; speedup vs baseline: 2.0542x; 2.0542x over previous
//
#include <hip/hip_runtime.h>
#include <math.h>

typedef unsigned short u16;
typedef __attribute__((ext_vector_type(8))) short bf16x8;
typedef __attribute__((ext_vector_type(4))) float f32x4;

// ---- problem constants ----
constexpr int cB   = 2;
constexpr int cS   = 1024;
constexpr int cD   = 2048;
constexpr int cH   = 8;
constexpr int cHD  = 256;
constexpr int cKV  = 4;
constexpr int cGHD = 512;
constexpr int cGKV = 4;
constexpr int cROT = 128;
constexpr int cF   = 8192;
constexpr int cV   = 32000;
constexpr int cWIN = 512;
constexpr int cM   = cB * cS;   // 2048 token rows
constexpr float cEPS = 1e-6f;
constexpr size_t MB = 1024 * 1024;

__device__ inline u16 f2bf(float x) {
    unsigned u = __float_as_uint(x);
    u += 0x7fff + ((u >> 16) & 1);     // RNE
    return (u16)(u >> 16);
}
__device__ inline float bf2f(u16 v) { return __uint_as_float(((unsigned)v) << 16); }
// split: hi = bf16(v), lo = bf16(v - hi)
__device__ inline void splitbf(float v, u16& h, u16& l) {
    h = f2bf(v);
    l = f2bf(v - bf2f(h));
}

// ---------------------------------------------------------------------------
// embed lookup * sqrt(D)
// ---------------------------------------------------------------------------
__global__ void embed_kernel(const int* __restrict__ tok,
                             const float* __restrict__ emb,
                             float* __restrict__ out) {
    const int row = blockIdx.x;
    const int t = tok[row];
    const float* e = emb + (size_t)t * cD;
    float* o = out + (size_t)row * cD;
    const float sc = sqrtf((float)cD);
    for (int d = threadIdx.x; d < cD; d += blockDim.x) o[d] = e[d] * sc;
}

// ---------------------------------------------------------------------------
// row RMS norm fp32->fp32
// ---------------------------------------------------------------------------
__global__ void rms_kernel(const float* __restrict__ x,
                           const float* __restrict__ w,
                           float* __restrict__ out, int dim) {
    const int row = blockIdx.x;
    const float* xr = x + (size_t)row * dim;
    float* orow = out + (size_t)row * dim;
    float ss = 0.f;
    for (int d = threadIdx.x; d < dim; d += blockDim.x) { float v = xr[d]; ss += v * v; }
    for (int o = 32; o >= 1; o >>= 1) ss += __shfl_xor(ss, o);
    __shared__ float rb[8];
    if ((threadIdx.x & 63) == 0) rb[threadIdx.x >> 6] = ss;
    __syncthreads();
    ss = rb[0] + rb[1] + rb[2] + rb[3];
    const float r = rsqrtf(ss / dim + cEPS);
    for (int d = threadIdx.x; d < dim; d += blockDim.x)
        orow[d] = xr[d] * r * (w ? w[d] : 1.f);
}

// row RMS norm fp32 -> split-bf16 (two planes, lo at +ps)
__global__ void rms_bf16_kernel(const float* __restrict__ x,
                                const float* __restrict__ w,
                                u16* __restrict__ out, int dim, int ps) {
    const int row = blockIdx.x;
    const float* xr = x + (size_t)row * dim;
    const size_t base = (size_t)row * dim;
    float ss = 0.f;
    for (int d = threadIdx.x; d < dim; d += blockDim.x) { float v = xr[d]; ss += v * v; }
    for (int o = 32; o >= 1; o >>= 1) ss += __shfl_xor(ss, o);
    __shared__ float rb[8];
    if ((threadIdx.x & 63) == 0) rb[threadIdx.x >> 6] = ss;
    __syncthreads();
    ss = rb[0] + rb[1] + rb[2] + rb[3];
    const float r = rsqrtf(ss / dim + cEPS);
    for (int d = threadIdx.x; d < dim; d += blockDim.x) {
        u16 h, l;
        splitbf(xr[d] * r * (w ? w[d] : 1.f), h, l);
        out[base + d] = h;
        out[(size_t)ps + base + d] = l;
    }
}

// out = (res + x * rsqrt(mean(x^2)+eps) * w) * (scal or 1)   (out may alias res)
__global__ void rms_add_kernel(const float* __restrict__ res,
                               const float* __restrict__ x,
                               const float* __restrict__ w,
                               const float* __restrict__ scal,
                               float* __restrict__ out, int dim) {
    const int row = blockIdx.x;
    const float* xr = x + (size_t)row * dim;
    const float* rr = res + (size_t)row * dim;
    float* orow = out + (size_t)row * dim;
    float ss = 0.f;
    for (int d = threadIdx.x; d < dim; d += blockDim.x) { float v = xr[d]; ss += v * v; }
    for (int o = 32; o >= 1; o >>= 1) ss += __shfl_xor(ss, o);
    __shared__ float rb[8];
    if ((threadIdx.x & 63) == 0) rb[threadIdx.x >> 6] = ss;
    __syncthreads();
    ss = rb[0] + rb[1] + rb[2] + rb[3];
    const float r = rsqrtf(ss / dim + cEPS);
    const float sc = scal ? *scal : 1.f;
    for (int d = threadIdx.x; d < dim; d += blockDim.x)
        orow[d] = (rr[d] + xr[d] * r * w[d]) * sc;
}

// ---------------------------------------------------------------------------
// RoPE in place on first `rot` dims of each head row (fp32).
// ---------------------------------------------------------------------------
__global__ void rope_kernel(float* __restrict__ x, int NH, int HDIM, int rot, float theta) {
    const int row = blockIdx.x;
    const int s = (row / NH) % cS;
    float* xr = x + (size_t)row * HDIM;
    const int half = rot >> 1;
    for (int i = threadIdx.x; i < half; i += blockDim.x) {
        const float inv = powf(theta, -(2.f * i) / (float)rot);
        const float ang = (float)s * inv;
        const float c = cosf(ang), sn = sinf(ang);
        const float x1 = xr[2 * i], x2 = xr[2 * i + 1];
        xr[2 * i]     = x1 * c - x2 * sn;
        xr[2 * i + 1] = x1 * sn + x2 * c;
    }
}

// ---------------------------------------------------------------------------
// fp32 [K][N-chunk] (row stride ldin) -> split-bf16 [N][K] (lo plane at +ps)
// ---------------------------------------------------------------------------
__global__ __launch_bounds__(256) void tcast_kernel(const float* __restrict__ in,
                                                    u16* __restrict__ out,
                                                    int K, int N, int ldin, int ps) {
    __shared__ float t[32][33];
    const int kt = blockIdx.y * 32, nt = blockIdx.x * 32;
    const int tx = threadIdx.x & 31, ty = threadIdx.x >> 5;   // ty 0..7
#pragma unroll
    for (int j = 0; j < 4; ++j)
        t[ty + j * 8][tx] = in[(size_t)(kt + ty + j * 8) * ldin + nt + tx];
    __syncthreads();
#pragma unroll
    for (int j = 0; j < 4; ++j) {
        u16 h, l;
        splitbf(t[tx][ty + j * 8], h, l);
        const size_t idx = (size_t)(nt + ty + j * 8) * K + kt + tx;
        out[idx] = h;
        out[(size_t)ps + idx] = l;
    }
}

// fp32 -> split-bf16 elementwise (4 per thread), same layout
__global__ void cast_kernel(const float* __restrict__ in, u16* __restrict__ out,
                            int n, int ps) {
    const int i = blockIdx.x * blockDim.x + threadIdx.x;
    if (i * 4 >= n) return;
    const float4 v = *(const float4*)&in[(size_t)i * 4];
    u16 h[4], l[4];
    splitbf(v.x, h[0], l[0]); splitbf(v.y, h[1], l[1]);
    splitbf(v.z, h[2], l[2]); splitbf(v.w, h[3], l[3]);
    uint2 oh, ol;
    oh.x = (unsigned)h[0] | ((unsigned)h[1] << 16);
    oh.y = (unsigned)h[2] | ((unsigned)h[3] << 16);
    ol.x = (unsigned)l[0] | ((unsigned)l[1] << 16);
    ol.y = (unsigned)l[2] | ((unsigned)l[3] << 16);
    *(uint2*)&out[(size_t)i * 4] = oh;
    *(uint2*)&out[(size_t)ps + (size_t)i * 4] = ol;
}

// ---------------------------------------------------------------------------
// split-bf16 MFMA GEMM: C[M,N] = (A_hi+A_lo)[M,K] @ (B_hi+B_lo)[N,K]^T
// (drops lo*lo). 128x128 tile, BK=32, 256 threads, 3 MFMAs per frag pair.
// ---------------------------------------------------------------------------
template<bool BF16_OUT, bool ACCUM>
__global__ __launch_bounds__(256) void gemm_split(const u16* __restrict__ A,
                                                  const u16* __restrict__ Bt,
                                                  void* __restrict__ Cout,
                                                  int M, int N, int K, int ldc,
                                                  int aps, int bps, int cps) {
    __shared__ u16 As[2][128 * 32];
    __shared__ u16 Bs[2][128 * 32];
    const int bm = blockIdx.y * 128;
    const int bn = blockIdx.x * 128;
    const int tid = threadIdx.x;
    const int lane = tid & 63;
    const int w = tid >> 6;
    const int wr = (w >> 1) * 64, wc = (w & 1) * 64;
    const int r15 = lane & 15, hi16 = lane >> 4;

    f32x4 acc[4][4];
#pragma unroll
    for (int m = 0; m < 4; ++m)
#pragma unroll
        for (int n = 0; n < 4; ++n) acc[m][n] = (f32x4){0.f, 0.f, 0.f, 0.f};

    const int c0 = tid, c1 = tid + 256;
    const int ar0 = c0 >> 2, ak0 = (c0 & 3) * 8;
    const int ar1 = c1 >> 2, ak1 = (c1 & 3) * 8;
    const u16* Al = A + aps;
    const u16* Bl = Bt + bps;

    for (int k0 = 0; k0 < K; k0 += 32) {
        uint4 v0 = *(const uint4*)&A [(size_t)(bm + ar0) * K + k0 + ak0];
        uint4 v1 = *(const uint4*)&A [(size_t)(bm + ar1) * K + k0 + ak1];
        uint4 v2 = *(const uint4*)&Al[(size_t)(bm + ar0) * K + k0 + ak0];
        uint4 v3 = *(const uint4*)&Al[(size_t)(bm + ar1) * K + k0 + ak1];
        uint4 v4 = *(const uint4*)&Bt[(size_t)(bn + ar0) * K + k0 + ak0];
        uint4 v5 = *(const uint4*)&Bt[(size_t)(bn + ar1) * K + k0 + ak1];
        uint4 v6 = *(const uint4*)&Bl[(size_t)(bn + ar0) * K + k0 + ak0];
        uint4 v7 = *(const uint4*)&Bl[(size_t)(bn + ar1) * K + k0 + ak1];
        __syncthreads();                    // prev tile fully consumed
        *(uint4*)&As[0][c0 * 8] = v0;
        *(uint4*)&As[0][c1 * 8] = v1;
        *(uint4*)&As[1][c0 * 8] = v2;
        *(uint4*)&As[1][c1 * 8] = v3;
        *(uint4*)&Bs[0][c0 * 8] = v4;
        *(uint4*)&Bs[0][c1 * 8] = v5;
        *(uint4*)&Bs[1][c0 * 8] = v6;
        *(uint4*)&Bs[1][c1 * 8] = v7;
        __syncthreads();
        bf16x8 ah[4], al[4], bh[4], bl[4];
#pragma unroll
        for (int m = 0; m < 4; ++m) {
            ah[m] = *(const bf16x8*)&As[0][(wr + m * 16 + r15) * 32 + hi16 * 8];
            al[m] = *(const bf16x8*)&As[1][(wr + m * 16 + r15) * 32 + hi16 * 8];
        }
#pragma unroll
        for (int n = 0; n < 4; ++n) {
            bh[n] = *(const bf16x8*)&Bs[0][(wc + n * 16 + r15) * 32 + hi16 * 8];
            bl[n] = *(const bf16x8*)&Bs[1][(wc + n * 16 + r15) * 32 + hi16 * 8];
        }
#pragma unroll
        for (int m = 0; m < 4; ++m)
#pragma unroll
            for (int n = 0; n < 4; ++n) {
                acc[m][n] = __builtin_amdgcn_mfma_f32_16x16x32_bf16(ah[m], bl[n], acc[m][n], 0, 0, 0);
                acc[m][n] = __builtin_amdgcn_mfma_f32_16x16x32_bf16(al[m], bh[n], acc[m][n], 0, 0, 0);
                acc[m][n] = __builtin_amdgcn_mfma_f32_16x16x32_bf16(ah[m], bh[n], acc[m][n], 0, 0, 0);
            }
    }
#pragma unroll
    for (int m = 0; m < 4; ++m)
#pragma unroll
        for (int n = 0; n < 4; ++n)
#pragma unroll
            for (int r = 0; r < 4; ++r) {
                const int row = bm + wr + m * 16 + hi16 * 4 + r;
                const int col = bn + wc + n * 16 + r15;
                float v = acc[m][n][r];
                if (BF16_OUT) {
                    u16 h, l;
                    splitbf(v, h, l);
                    ((u16*)Cout)[(size_t)row * ldc + col] = h;
                    ((u16*)Cout)[(size_t)cps + (size_t)row * ldc + col] = l;
                } else {
                    float* cp = (float*)Cout + (size_t)row * ldc + col;
                    if (ACCUM) v += *cp;
                    *cp = v;
                }
            }
}

// ---------------------------------------------------------------------------
// attention (fp32 Q/K/V, split-bf16 out): one block per (q, h, b).
// ---------------------------------------------------------------------------
template<int HDIM>
__global__ __launch_bounds__(256) void attn_kernel(const float* __restrict__ Q,
                                                   const float* __restrict__ K,
                                                   const float* __restrict__ V,
                                                   u16* __restrict__ O, int ops,
                                                   const int* __restrict__ tlen,
                                                   int KVH, int win) {
    const int q = blockIdx.x, h = blockIdx.y, b = blockIdx.z;
    const int kh = h / (cH / KVH);
    __shared__ float qs[HDIM];
    __shared__ float sc[cS];
    __shared__ float rb[8];
    const int tid = threadIdx.x;
    const int lane = tid & 63, wid = tid >> 6;

    const float* qrow = Q + (((size_t)b * cS + q) * cH + h) * HDIM;
    for (int d = tid; d < HDIM; d += 256) qs[d] = qrow[d];
    __syncthreads();

    const int tl = tlen[b];
    const int kmax = min(q, tl - 1);
    const int kmin = (win > 0) ? max(0, q - win + 1) : 0;
    const int n = kmax - kmin + 1;

    for (int k = kmin + wid; k <= kmax; k += 4) {
        const float* kr = K + (((size_t)b * cS + k) * KVH + kh) * HDIM;
        float p = 0.f;
#pragma unroll
        for (int d = lane; d < HDIM; d += 64) p += qs[d] * kr[d];
        for (int o = 32; o >= 1; o >>= 1) p += __shfl_xor(p, o);
        if (lane == 0) sc[k - kmin] = p;
    }
    __syncthreads();

    float m = -1e30f;
    for (int i = tid; i < n; i += 256) m = fmaxf(m, sc[i]);
    for (int o = 32; o >= 1; o >>= 1) m = fmaxf(m, __shfl_xor(m, o));
    if (lane == 0) rb[wid] = m;
    __syncthreads();
    m = fmaxf(fmaxf(rb[0], rb[1]), fmaxf(rb[2], rb[3]));

    float ssum = 0.f;
    for (int i = tid; i < n; i += 256) { float e = expf(sc[i] - m); sc[i] = e; ssum += e; }
    for (int o = 32; o >= 1; o >>= 1) ssum += __shfl_xor(ssum, o);
    if (lane == 0) rb[4 + wid] = ssum;
    __syncthreads();
    ssum = rb[4] + rb[5] + rb[6] + rb[7];
    const float inv = 1.f / ssum;

    for (int d = tid; d < HDIM; d += 256) {
        float acc = 0.f;
        for (int k = kmin; k <= kmax; ++k)
            acc += sc[k - kmin] * V[(((size_t)b * cS + k) * KVH + kh) * HDIM + d];
        const size_t idx = (((size_t)b * cS + q) * cH + h) * HDIM + d;
        u16 hh, ll;
        splitbf(acc * inv, hh, ll);
        O[idx] = hh;
        O[(size_t)ops + idx] = ll;
    }
}

// ---------------------------------------------------------------------------
// gated FFN elementwise on split-bf16: out = gelu_tanh(g) * u  (4/thread)
// ---------------------------------------------------------------------------
__global__ void gelumul_kernel(const u16* __restrict__ g, const u16* __restrict__ u,
                               u16* __restrict__ out, int n, int ps) {
    const int i = blockIdx.x * blockDim.x + threadIdx.x;
    if (i * 4 >= n) return;
    const uint2 gh = *(const uint2*)&g[(size_t)i * 4];
    const uint2 gl = *(const uint2*)&g[(size_t)ps + (size_t)i * 4];
    const uint2 uh = *(const uint2*)&u[(size_t)i * 4];
    const uint2 ul = *(const uint2*)&u[(size_t)ps + (size_t)i * 4];
    auto gelu = [](float v) {
        const float t = tanhf(0.7978845608028654f * (v + 0.044715f * v * v * v));
        return 0.5f * v * (1.f + t);
    };
    float gv[4] = { bf2f((u16)(gh.x & 0xffff)) + bf2f((u16)(gl.x & 0xffff)),
                    bf2f((u16)(gh.x >> 16))    + bf2f((u16)(gl.x >> 16)),
                    bf2f((u16)(gh.y & 0xffff)) + bf2f((u16)(gl.y & 0xffff)),
                    bf2f((u16)(gh.y >> 16))    + bf2f((u16)(gl.y >> 16)) };
    float uv[4] = { bf2f((u16)(uh.x & 0xffff)) + bf2f((u16)(ul.x & 0xffff)),
                    bf2f((u16)(uh.x >> 16))    + bf2f((u16)(ul.x >> 16)),
                    bf2f((u16)(uh.y & 0xffff)) + bf2f((u16)(ul.y & 0xffff)),
                    bf2f((u16)(uh.y >> 16))    + bf2f((u16)(ul.y >> 16)) };
    u16 h[4], l[4];
#pragma unroll
    for (int j = 0; j < 4; ++j) splitbf(gelu(gv[j]) * uv[j], h[j], l[j]);
    uint2 oh, ol;
    oh.x = (unsigned)h[0] | ((unsigned)h[1] << 16);
    oh.y = (unsigned)h[2] | ((unsigned)h[3] << 16);
    ol.x = (unsigned)l[0] | ((unsigned)l[1] << 16);
    ol.y = (unsigned)l[2] | ((unsigned)l[3] << 16);
    *(uint2*)&out[(size_t)i * 4] = oh;
    *(uint2*)&out[(size_t)ps + (size_t)i * 4] = ol;
}

// ---------------------------------------------------------------------------
extern "C" void kernel_launch(void* const* d_in, const int* in_sizes, int n_in,
                              void* d_out, int out_size, void* d_ws, size_t ws_size,
                              hipStream_t stream) {
    (void)in_sizes; (void)n_in; (void)out_size; (void)ws_size;
    const int*   tokens = (const int*)  d_in[0];
    const int*   tlen   = (const int*)  d_in[1];
    const float* embed  = (const float*)d_in[2];
    const float* norm_w = (const float*)d_in[3];
    const float* s_wq   = (const float*)d_in[4];
    const float* s_wk   = (const float*)d_in[5];
    const float* s_wv   = (const float*)d_in[6];
    const float* s_wo   = (const float*)d_in[7];
    const float* s_qn   = (const float*)d_in[8];
    const float* s_kn   = (const float*)d_in[9];
    const float* s_wg   = (const float*)d_in[10];
    const float* s_wu   = (const float*)d_in[11];
    const float* s_wd   = (const float*)d_in[12];
    const float* s_ln1  = (const float*)d_in[13];
    const float* s_ln2  = (const float*)d_in[14];
    const float* s_ln3  = (const float*)d_in[15];
    const float* s_ln4  = (const float*)d_in[16];
    const float* s_scal = (const float*)d_in[17];
    const float* g_wq   = (const float*)d_in[18];
    const float* g_wk   = (const float*)d_in[19];
    const float* g_wo   = (const float*)d_in[20];
    const float* g_qn   = (const float*)d_in[21];
    const float* g_kn   = (const float*)d_in[22];
    const float* g_wg   = (const float*)d_in[23];
    const float* g_wu   = (const float*)d_in[24];
    const float* g_wd   = (const float*)d_in[25];
    const float* g_ln1  = (const float*)d_in[26];
    const float* g_ln2  = (const float*)d_in[27];
    const float* g_ln3  = (const float*)d_in[28];
    const float* g_ln4  = (const float*)d_in[29];
    const float* g_scal = (const float*)d_in[30];

    // workspace layout (160 MiB peak):
    //   [0,16)    x    fp32 residual
    //   [16,32)   ab   split-bf16 normed activations (cM x cD, 2 planes)
    //   [32,48)   r0   fp32: k / oproj-out / ffn-out accumulator
    //   [48,64)   r1   fp32: v
    //   [64,96)   bb   split-bf16 weight panels (<=2048x4096 2pl)
    //   [96,128)  t0   fp32 q  |  split-bf16 gate chunk
    //   [128,160) t1   split-bf16 attn-out |  split-bf16 up chunk
    char* w8 = (char*)d_ws;
    float* x   = (float*)(w8);
    u16*   ab  = (u16*)(w8 + 16 * MB);
    float* r0  = (float*)(w8 + 32 * MB);
    float* r1  = (float*)(w8 + 48 * MB);
    u16*   bb  = (u16*)(w8 + 64 * MB);
    float* t0f = (float*)(w8 + 96 * MB);
    u16*   t0b = (u16*)(w8 + 96 * MB);
    u16*   t1b = (u16*)(w8 + 128 * MB);

    constexpr int PS_AB = cM * cD;          // 4,194,304
    constexpr int CF    = 4096;             // FFN N-chunk
    constexpr int CHV   = 3200;             // logits N-chunk (10 chunks)

    auto tcast = [&](const float* in, u16* outp, int K, int N, int ldin, int ps) {
        tcast_kernel<<<dim3(N / 32, K / 32), 256, 0, stream>>>(in, outp, K, N, ldin, ps);
    };
    auto gemmF = [&](const u16* A, const u16* Bt, float* C, int M, int N, int K,
                     int ldc, int aps, int bps, bool accum) {
        if (accum)
            gemm_split<false, true><<<dim3(N / 128, M / 128), 256, 0, stream>>>(
                A, Bt, C, M, N, K, ldc, aps, bps, 0);
        else
            gemm_split<false, false><<<dim3(N / 128, M / 128), 256, 0, stream>>>(
                A, Bt, C, M, N, K, ldc, aps, bps, 0);
    };
    auto gemmB = [&](const u16* A, const u16* Bt, u16* C, int M, int N, int K,
                     int ldc, int aps, int bps, int cps) {
        gemm_split<true, false><<<dim3(N / 128, M / 128), 256, 0, stream>>>(
            A, Bt, C, M, N, K, ldc, aps, bps, cps);
    };

    embed_kernel<<<cM, 256, 0, stream>>>(tokens, embed, x);

    // ================= block 1: sliding-window =================
    rms_bf16_kernel<<<cM, 256, 0, stream>>>(x, s_ln1, ab, cD, PS_AB);
    tcast(s_wq, bb, cD, cH * cHD, cH * cHD, cD * cH * cHD);
    gemmF(ab, bb, t0f, cM, cH * cHD, cD, cH * cHD, PS_AB, cD * cH * cHD, false);
    tcast(s_wk, bb, cD, cKV * cHD, cKV * cHD, cD * cKV * cHD);
    gemmF(ab, bb, r0, cM, cKV * cHD, cD, cKV * cHD, PS_AB, cD * cKV * cHD, false);
    tcast(s_wv, bb, cD, cKV * cHD, cKV * cHD, cD * cKV * cHD);
    gemmF(ab, bb, r1, cM, cKV * cHD, cD, cKV * cHD, PS_AB, cD * cKV * cHD, false);
    rms_kernel<<<cM * cKV, 256, 0, stream>>>(r1, nullptr, r1, cHD);     // xv = rms_ns(h@wv)
    rms_kernel<<<cM * cH, 256, 0, stream>>>(t0f, s_qn, t0f, cHD);
    rms_kernel<<<cM * cKV, 256, 0, stream>>>(r0, s_kn, r0, cHD);
    rope_kernel<<<cM * cH, 128, 0, stream>>>(t0f, cH, cHD, cHD, 10000.f);
    rope_kernel<<<cM * cKV, 128, 0, stream>>>(r0, cKV, cHD, cHD, 10000.f);
    attn_kernel<cHD><<<dim3(cS, cH, cB), 256, 0, stream>>>(t0f, r0, r1, t1b, cM * 2048,
                                                           tlen, cKV, cWIN);
    tcast(s_wo, bb, cH * cHD, cD, cD, cH * cHD * cD);
    gemmF(t1b, bb, r0, cM, cD, cH * cHD, cD, cM * 2048, cH * cHD * cD, false);
    rms_add_kernel<<<cM, 256, 0, stream>>>(x, r0, s_ln2, nullptr, x, cD);
    rms_bf16_kernel<<<cM, 256, 0, stream>>>(x, s_ln3, ab, cD, PS_AB);
    for (int c = 0; c < cF / CF; ++c) {
        tcast(s_wg + (size_t)c * CF, bb, cD, CF, cF, cD * CF);
        gemmB(ab, bb, t0b, cM, CF, cD, CF, PS_AB, cD * CF, cM * CF);
        tcast(s_wu + (size_t)c * CF, bb, cD, CF, cF, cD * CF);
        gemmB(ab, bb, t1b, cM, CF, cD, CF, PS_AB, cD * CF, cM * CF);
        gelumul_kernel<<<(cM * CF / 4 + 255) / 256, 256, 0, stream>>>(t0b, t1b, t0b,
                                                                     cM * CF, cM * CF);
        tcast(s_wd + (size_t)c * CF * cD, bb, CF, cD, cD, CF * cD);
        gemmF(t0b, bb, r0, cM, cD, CF, cD, cM * CF, CF * cD, c > 0);
    }
    rms_add_kernel<<<cM, 256, 0, stream>>>(x, r0, s_ln4, s_scal, x, cD);

    // ================= block 2: global =================
    rms_bf16_kernel<<<cM, 256, 0, stream>>>(x, g_ln1, ab, cD, PS_AB);
    tcast(g_wq, bb, cD, cH * cGHD, cH * cGHD, cD * cH * cGHD);
    gemmF(ab, bb, t0f, cM, cH * cGHD, cD, cH * cGHD, PS_AB, cD * cH * cGHD, false);
    tcast(g_wk, bb, cD, cGKV * cGHD, cGKV * cGHD, cD * cGKV * cGHD);
    gemmF(ab, bb, r0, cM, cGKV * cGHD, cD, cGKV * cGHD, PS_AB, cD * cGKV * cGHD, false);
    rms_kernel<<<cM * cGKV, 256, 0, stream>>>(r0, nullptr, r1, cGHD);   // xv = rms_ns(raw xk)
    rms_kernel<<<cM * cH, 256, 0, stream>>>(t0f, g_qn, t0f, cGHD);
    rms_kernel<<<cM * cGKV, 256, 0, stream>>>(r0, g_kn, r0, cGHD);
    rope_kernel<<<cM * cH, 64, 0, stream>>>(t0f, cH, cGHD, cROT, 1000000.f);
    rope_kernel<<<cM * cGKV, 64, 0, stream>>>(r0, cGKV, cGHD, cROT, 1000000.f);
    attn_kernel<cGHD><<<dim3(cS, cH, cB), 256, 0, stream>>>(t0f, r0, r1, t1b, cM * 4096,
                                                            tlen, cGKV, 0);
    tcast(g_wo, bb, cH * cGHD, cD, cD, cH * cGHD * cD);
    gemmF(t1b, bb, r0, cM, cD, cH * cGHD, cD, cM * 4096, cH * cGHD * cD, false);
    rms_add_kernel<<<cM, 256, 0, stream>>>(x, r0, g_ln2, nullptr, x, cD);
    rms_bf16_kernel<<<cM, 256, 0, stream>>>(x, g_ln3, ab, cD, PS_AB);
    for (int c = 0; c < cF / CF; ++c) {
        tcast(g_wg + (size_t)c * CF, bb, cD, CF, cF, cD * CF);
        gemmB(ab, bb, t0b, cM, CF, cD, CF, PS_AB, cD * CF, cM * CF);
        tcast(g_wu + (size_t)c * CF, bb, cD, CF, cF, cD * CF);
        gemmB(ab, bb, t1b, cM, CF, cD, CF, PS_AB, cD * CF, cM * CF);
        gelumul_kernel<<<(cM * CF / 4 + 255) / 256, 256, 0, stream>>>(t0b, t1b, t0b,
                                                                     cM * CF, cM * CF);
        tcast(g_wd + (size_t)c * CF * cD, bb, CF, cD, cD, CF * cD);
        gemmF(t0b, bb, r0, cM, cD, CF, cD, cM * CF, CF * cD, c > 0);
    }
    rms_add_kernel<<<cM, 256, 0, stream>>>(x, r0, g_ln4, g_scal, x, cD);

    // ================= final norm + logits (chunked over V) =================
    rms_bf16_kernel<<<cM, 256, 0, stream>>>(x, norm_w, ab, cD, PS_AB);
    for (int c = 0; c < cV / CHV; ++c) {
        cast_kernel<<<(CHV * cD / 4 + 255) / 256, 256, 0, stream>>>(
            embed + (size_t)c * CHV * cD, bb, CHV * cD, CHV * cD);
        gemmF(ab, bb, (float*)d_out + (size_t)c * CHV, cM, CHV, cD, cV,
              PS_AB, CHV * cD, false);
    }
}

// Round 4
// 4267.716 us; speedup vs baseline: 3.7370x; 1.8192x over previous
//
#include <hip/hip_runtime.h>
#include <math.h>

typedef unsigned short u16;
typedef __attribute__((ext_vector_type(8))) short bf16x8;
typedef __attribute__((ext_vector_type(4))) float f32x4;

// ---- problem constants ----
constexpr int cB   = 2;
constexpr int cS   = 1024;
constexpr int cD   = 2048;
constexpr int cH   = 8;
constexpr int cHD  = 256;
constexpr int cKV  = 4;
constexpr int cGHD = 512;
constexpr int cGKV = 4;
constexpr int cROT = 128;
constexpr int cF   = 8192;
constexpr int cV   = 32000;
constexpr int cWIN = 512;
constexpr int cM   = cB * cS;   // 2048 token rows
constexpr float cEPS = 1e-6f;
constexpr size_t MB = 1024 * 1024;

__device__ inline u16 f2bf(float x) {
    unsigned u = __float_as_uint(x);
    u += 0x7fff + ((u >> 16) & 1);     // RNE
    return (u16)(u >> 16);
}
__device__ inline float bf2f(u16 v) { return __uint_as_float(((unsigned)v) << 16); }
// split: hi = bf16(v), lo = bf16(v - hi)
__device__ inline void splitbf(float v, u16& h, u16& l) {
    h = f2bf(v);
    l = f2bf(v - bf2f(h));
}

// ---------------------------------------------------------------------------
// embed lookup * sqrt(D)
// ---------------------------------------------------------------------------
__global__ void embed_kernel(const int* __restrict__ tok,
                             const float* __restrict__ emb,
                             float* __restrict__ out) {
    const int row = blockIdx.x;
    const int t = tok[row];
    const float* e = emb + (size_t)t * cD;
    float* o = out + (size_t)row * cD;
    const float sc = sqrtf((float)cD);
    for (int d = threadIdx.x; d < cD; d += blockDim.x) o[d] = e[d] * sc;
}

// ---------------------------------------------------------------------------
// row RMS norm fp32->fp32
// ---------------------------------------------------------------------------
__global__ void rms_kernel(const float* __restrict__ x,
                           const float* __restrict__ w,
                           float* __restrict__ out, int dim) {
    const int row = blockIdx.x;
    const float* xr = x + (size_t)row * dim;
    float* orow = out + (size_t)row * dim;
    float ss = 0.f;
    for (int d = threadIdx.x; d < dim; d += blockDim.x) { float v = xr[d]; ss += v * v; }
    for (int o = 32; o >= 1; o >>= 1) ss += __shfl_xor(ss, o);
    __shared__ float rb[8];
    if ((threadIdx.x & 63) == 0) rb[threadIdx.x >> 6] = ss;
    __syncthreads();
    ss = rb[0] + rb[1] + rb[2] + rb[3];
    const float r = rsqrtf(ss / dim + cEPS);
    for (int d = threadIdx.x; d < dim; d += blockDim.x)
        orow[d] = xr[d] * r * (w ? w[d] : 1.f);
}

// row RMS norm fp32 -> split-bf16 (two planes, lo at +ps)
__global__ void rms_bf16_kernel(const float* __restrict__ x,
                                const float* __restrict__ w,
                                u16* __restrict__ out, int dim, int ps) {
    const int row = blockIdx.x;
    const float* xr = x + (size_t)row * dim;
    const size_t base = (size_t)row * dim;
    float ss = 0.f;
    for (int d = threadIdx.x; d < dim; d += blockDim.x) { float v = xr[d]; ss += v * v; }
    for (int o = 32; o >= 1; o >>= 1) ss += __shfl_xor(ss, o);
    __shared__ float rb[8];
    if ((threadIdx.x & 63) == 0) rb[threadIdx.x >> 6] = ss;
    __syncthreads();
    ss = rb[0] + rb[1] + rb[2] + rb[3];
    const float r = rsqrtf(ss / dim + cEPS);
    for (int d = threadIdx.x; d < dim; d += blockDim.x) {
        u16 h, l;
        splitbf(xr[d] * r * (w ? w[d] : 1.f), h, l);
        out[base + d] = h;
        out[(size_t)ps + base + d] = l;
    }
}

// out = (res + x * rsqrt(mean(x^2)+eps) * w) * (scal or 1)   (out may alias res)
__global__ void rms_add_kernel(const float* __restrict__ res,
                               const float* __restrict__ x,
                               const float* __restrict__ w,
                               const float* __restrict__ scal,
                               float* __restrict__ out, int dim) {
    const int row = blockIdx.x;
    const float* xr = x + (size_t)row * dim;
    const float* rr = res + (size_t)row * dim;
    float* orow = out + (size_t)row * dim;
    float ss = 0.f;
    for (int d = threadIdx.x; d < dim; d += blockDim.x) { float v = xr[d]; ss += v * v; }
    for (int o = 32; o >= 1; o >>= 1) ss += __shfl_xor(ss, o);
    __shared__ float rb[8];
    if ((threadIdx.x & 63) == 0) rb[threadIdx.x >> 6] = ss;
    __syncthreads();
    ss = rb[0] + rb[1] + rb[2] + rb[3];
    const float r = rsqrtf(ss / dim + cEPS);
    const float sc = scal ? *scal : 1.f;
    for (int d = threadIdx.x; d < dim; d += blockDim.x)
        orow[d] = (rr[d] + xr[d] * r * w[d]) * sc;
}

// ---------------------------------------------------------------------------
// RoPE in place on first `rot` dims of each head row (fp32).
// ---------------------------------------------------------------------------
__global__ void rope_kernel(float* __restrict__ x, int NH, int HDIM, int rot, float theta) {
    const int row = blockIdx.x;
    const int s = (row / NH) % cS;
    float* xr = x + (size_t)row * HDIM;
    const int half = rot >> 1;
    for (int i = threadIdx.x; i < half; i += blockDim.x) {
        const float inv = powf(theta, -(2.f * i) / (float)rot);
        const float ang = (float)s * inv;
        const float c = cosf(ang), sn = sinf(ang);
        const float x1 = xr[2 * i], x2 = xr[2 * i + 1];
        xr[2 * i]     = x1 * c - x2 * sn;
        xr[2 * i + 1] = x1 * sn + x2 * c;
    }
}

// ---------------------------------------------------------------------------
// fp32 [K][N-chunk] (row stride ldin) -> split-bf16 [N][K] (lo plane at +ps)
// ---------------------------------------------------------------------------
__global__ __launch_bounds__(256) void tcast_kernel(const float* __restrict__ in,
                                                    u16* __restrict__ out,
                                                    int K, int N, int ldin, int ps) {
    __shared__ float t[32][33];
    const int kt = blockIdx.y * 32, nt = blockIdx.x * 32;
    const int tx = threadIdx.x & 31, ty = threadIdx.x >> 5;   // ty 0..7
#pragma unroll
    for (int j = 0; j < 4; ++j)
        t[ty + j * 8][tx] = in[(size_t)(kt + ty + j * 8) * ldin + nt + tx];
    __syncthreads();
#pragma unroll
    for (int j = 0; j < 4; ++j) {
        u16 h, l;
        splitbf(t[tx][ty + j * 8], h, l);
        const size_t idx = (size_t)(nt + ty + j * 8) * K + kt + tx;
        out[idx] = h;
        out[(size_t)ps + idx] = l;
    }
}

// fp32 -> split-bf16 elementwise (4 per thread)
__global__ void cast_kernel(const float* __restrict__ in, u16* __restrict__ out,
                            int n, int ps) {
    const int i = blockIdx.x * blockDim.x + threadIdx.x;
    if (i * 4 >= n) return;
    const float4 v = *(const float4*)&in[(size_t)i * 4];
    u16 h[4], l[4];
    splitbf(v.x, h[0], l[0]); splitbf(v.y, h[1], l[1]);
    splitbf(v.z, h[2], l[2]); splitbf(v.w, h[3], l[3]);
    uint2 oh, ol;
    oh.x = (unsigned)h[0] | ((unsigned)h[1] << 16);
    oh.y = (unsigned)h[2] | ((unsigned)h[3] << 16);
    ol.x = (unsigned)l[0] | ((unsigned)l[1] << 16);
    ol.y = (unsigned)l[2] | ((unsigned)l[3] << 16);
    *(uint2*)&out[(size_t)i * 4] = oh;
    *(uint2*)&out[(size_t)ps + (size_t)i * 4] = ol;
}

// V fp32 [B,S,KVH,HDIM] -> Vt split-bf16 [B*KVH, HDIM, S] (lo at +vps)
__global__ __launch_bounds__(256) void vtrans_kernel(const float* __restrict__ V,
                                                     u16* __restrict__ Vt,
                                                     int HDIM, int KVH, int vps) {
    __shared__ float t[32][33];
    const int bk = blockIdx.z;
    const int b = bk / KVH, kh = bk % KVH;
    const int st = blockIdx.y * 32, dt = blockIdx.x * 32;
    const int tx = threadIdx.x & 31, ty = threadIdx.x >> 5;
#pragma unroll
    for (int j = 0; j < 4; ++j)
        t[ty + j * 8][tx] = V[((size_t)(b * cS + st + ty + j * 8) * KVH + kh) * HDIM + dt + tx];
    __syncthreads();
#pragma unroll
    for (int j = 0; j < 4; ++j) {
        u16 h, l;
        splitbf(t[tx][ty + j * 8], h, l);
        const size_t idx = ((size_t)bk * HDIM + dt + ty + j * 8) * cS + st + tx;
        Vt[idx] = h;
        Vt[(size_t)vps + idx] = l;
    }
}

// ---------------------------------------------------------------------------
// split-bf16 MFMA GEMM: C[M,N] = (A_hi+A_lo)[M,K] @ (B_hi+B_lo)[N,K]^T
// (drops lo*lo). 128x128 tile, BK=32, 256 threads, 3 MFMAs per frag pair.
// ---------------------------------------------------------------------------
template<bool BF16_OUT, bool ACCUM>
__global__ __launch_bounds__(256) void gemm_split(const u16* __restrict__ A,
                                                  const u16* __restrict__ Bt,
                                                  void* __restrict__ Cout,
                                                  int M, int N, int K, int ldc,
                                                  int aps, int bps, int cps) {
    __shared__ u16 As[2][128 * 32];
    __shared__ u16 Bs[2][128 * 32];
    const int bm = blockIdx.y * 128;
    const int bn = blockIdx.x * 128;
    const int tid = threadIdx.x;
    const int lane = tid & 63;
    const int w = tid >> 6;
    const int wr = (w >> 1) * 64, wc = (w & 1) * 64;
    const int r15 = lane & 15, hi16 = lane >> 4;

    f32x4 acc[4][4];
#pragma unroll
    for (int m = 0; m < 4; ++m)
#pragma unroll
        for (int n = 0; n < 4; ++n) acc[m][n] = (f32x4){0.f, 0.f, 0.f, 0.f};

    const int c0 = tid, c1 = tid + 256;
    const int ar0 = c0 >> 2, ak0 = (c0 & 3) * 8;
    const int ar1 = c1 >> 2, ak1 = (c1 & 3) * 8;
    const u16* Al = A + aps;
    const u16* Bl = Bt + bps;

    for (int k0 = 0; k0 < K; k0 += 32) {
        uint4 v0 = *(const uint4*)&A [(size_t)(bm + ar0) * K + k0 + ak0];
        uint4 v1 = *(const uint4*)&A [(size_t)(bm + ar1) * K + k0 + ak1];
        uint4 v2 = *(const uint4*)&Al[(size_t)(bm + ar0) * K + k0 + ak0];
        uint4 v3 = *(const uint4*)&Al[(size_t)(bm + ar1) * K + k0 + ak1];
        uint4 v4 = *(const uint4*)&Bt[(size_t)(bn + ar0) * K + k0 + ak0];
        uint4 v5 = *(const uint4*)&Bt[(size_t)(bn + ar1) * K + k0 + ak1];
        uint4 v6 = *(const uint4*)&Bl[(size_t)(bn + ar0) * K + k0 + ak0];
        uint4 v7 = *(const uint4*)&Bl[(size_t)(bn + ar1) * K + k0 + ak1];
        __syncthreads();
        *(uint4*)&As[0][c0 * 8] = v0;
        *(uint4*)&As[0][c1 * 8] = v1;
        *(uint4*)&As[1][c0 * 8] = v2;
        *(uint4*)&As[1][c1 * 8] = v3;
        *(uint4*)&Bs[0][c0 * 8] = v4;
        *(uint4*)&Bs[0][c1 * 8] = v5;
        *(uint4*)&Bs[1][c0 * 8] = v6;
        *(uint4*)&Bs[1][c1 * 8] = v7;
        __syncthreads();
        bf16x8 ah[4], al[4], bh[4], bl[4];
#pragma unroll
        for (int m = 0; m < 4; ++m) {
            ah[m] = *(const bf16x8*)&As[0][(wr + m * 16 + r15) * 32 + hi16 * 8];
            al[m] = *(const bf16x8*)&As[1][(wr + m * 16 + r15) * 32 + hi16 * 8];
        }
#pragma unroll
        for (int n = 0; n < 4; ++n) {
            bh[n] = *(const bf16x8*)&Bs[0][(wc + n * 16 + r15) * 32 + hi16 * 8];
            bl[n] = *(const bf16x8*)&Bs[1][(wc + n * 16 + r15) * 32 + hi16 * 8];
        }
#pragma unroll
        for (int m = 0; m < 4; ++m)
#pragma unroll
            for (int n = 0; n < 4; ++n) {
                acc[m][n] = __builtin_amdgcn_mfma_f32_16x16x32_bf16(ah[m], bl[n], acc[m][n], 0, 0, 0);
                acc[m][n] = __builtin_amdgcn_mfma_f32_16x16x32_bf16(al[m], bh[n], acc[m][n], 0, 0, 0);
                acc[m][n] = __builtin_amdgcn_mfma_f32_16x16x32_bf16(ah[m], bh[n], acc[m][n], 0, 0, 0);
            }
    }
#pragma unroll
    for (int m = 0; m < 4; ++m)
#pragma unroll
        for (int n = 0; n < 4; ++n)
#pragma unroll
            for (int r = 0; r < 4; ++r) {
                const int row = bm + wr + m * 16 + hi16 * 4 + r;
                const int col = bn + wc + n * 16 + r15;
                float v = acc[m][n][r];
                if (BF16_OUT) {
                    u16 h, l;
                    splitbf(v, h, l);
                    ((u16*)Cout)[(size_t)row * ldc + col] = h;
                    ((u16*)Cout)[(size_t)cps + (size_t)row * ldc + col] = l;
                } else {
                    float* cp = (float*)Cout + (size_t)row * ldc + col;
                    if (ACCUM) v += *cp;
                    *cp = v;
                }
            }
}

// ---------------------------------------------------------------------------
// batched QK^T scores: Sc[bh][q][kpos] fp32. Qb [B,S,H,HDIM] split, Kb
// [B,S,KVH,HDIM] split. Causal/window block skip.
// ---------------------------------------------------------------------------
__global__ __launch_bounds__(256) void qk_kernel(const u16* __restrict__ Qb, int qps,
                                                 const u16* __restrict__ Kb, int kps,
                                                 float* __restrict__ Sc,
                                                 int HDIM, int KVH, int win) {
    const int bm = blockIdx.y * 128;   // q tile
    const int bn = blockIdx.x * 128;   // k tile
    if (bn > bm + 127) return;                       // fully future
    if (win > 0 && bm - bn > win + 126) return;      // fully out of window
    const int bh = blockIdx.z;
    const int b = bh / cH, h = bh % cH;
    const int kh = h / (cH / KVH);

    __shared__ u16 As[2][128 * 32];
    __shared__ u16 Bs[2][128 * 32];
    const int tid = threadIdx.x;
    const int lane = tid & 63;
    const int w = tid >> 6;
    const int wr = (w >> 1) * 64, wc = (w & 1) * 64;
    const int r15 = lane & 15, hi16 = lane >> 4;

    const int lda = cH * HDIM, ldb = KVH * HDIM;
    const u16* Aq = Qb + ((size_t)b * cS * cH + h) * HDIM;
    const u16* Bk = Kb + ((size_t)b * cS * KVH + kh) * HDIM;

    f32x4 acc[4][4];
#pragma unroll
    for (int m = 0; m < 4; ++m)
#pragma unroll
        for (int n = 0; n < 4; ++n) acc[m][n] = (f32x4){0.f, 0.f, 0.f, 0.f};

    const int c0 = tid, c1 = tid + 256;
    const int ar0 = c0 >> 2, ak0 = (c0 & 3) * 8;
    const int ar1 = c1 >> 2, ak1 = (c1 & 3) * 8;

    for (int k0 = 0; k0 < HDIM; k0 += 32) {
        uint4 v0 = *(const uint4*)&Aq[(size_t)(bm + ar0) * lda + k0 + ak0];
        uint4 v1 = *(const uint4*)&Aq[(size_t)(bm + ar1) * lda + k0 + ak1];
        uint4 v2 = *(const uint4*)&Aq[(size_t)qps + (size_t)(bm + ar0) * lda + k0 + ak0];
        uint4 v3 = *(const uint4*)&Aq[(size_t)qps + (size_t)(bm + ar1) * lda + k0 + ak1];
        uint4 v4 = *(const uint4*)&Bk[(size_t)(bn + ar0) * ldb + k0 + ak0];
        uint4 v5 = *(const uint4*)&Bk[(size_t)(bn + ar1) * ldb + k0 + ak1];
        uint4 v6 = *(const uint4*)&Bk[(size_t)kps + (size_t)(bn + ar0) * ldb + k0 + ak0];
        uint4 v7 = *(const uint4*)&Bk[(size_t)kps + (size_t)(bn + ar1) * ldb + k0 + ak1];
        __syncthreads();
        *(uint4*)&As[0][c0 * 8] = v0;
        *(uint4*)&As[0][c1 * 8] = v1;
        *(uint4*)&As[1][c0 * 8] = v2;
        *(uint4*)&As[1][c1 * 8] = v3;
        *(uint4*)&Bs[0][c0 * 8] = v4;
        *(uint4*)&Bs[0][c1 * 8] = v5;
        *(uint4*)&Bs[1][c0 * 8] = v6;
        *(uint4*)&Bs[1][c1 * 8] = v7;
        __syncthreads();
        bf16x8 ah[4], al[4], bh4[4], bl4[4];
#pragma unroll
        for (int m = 0; m < 4; ++m) {
            ah[m] = *(const bf16x8*)&As[0][(wr + m * 16 + r15) * 32 + hi16 * 8];
            al[m] = *(const bf16x8*)&As[1][(wr + m * 16 + r15) * 32 + hi16 * 8];
        }
#pragma unroll
        for (int n = 0; n < 4; ++n) {
            bh4[n] = *(const bf16x8*)&Bs[0][(wc + n * 16 + r15) * 32 + hi16 * 8];
            bl4[n] = *(const bf16x8*)&Bs[1][(wc + n * 16 + r15) * 32 + hi16 * 8];
        }
#pragma unroll
        for (int m = 0; m < 4; ++m)
#pragma unroll
            for (int n = 0; n < 4; ++n) {
                acc[m][n] = __builtin_amdgcn_mfma_f32_16x16x32_bf16(ah[m], bl4[n], acc[m][n], 0, 0, 0);
                acc[m][n] = __builtin_amdgcn_mfma_f32_16x16x32_bf16(al[m], bh4[n], acc[m][n], 0, 0, 0);
                acc[m][n] = __builtin_amdgcn_mfma_f32_16x16x32_bf16(ah[m], bh4[n], acc[m][n], 0, 0, 0);
            }
    }
    float* Crow = Sc + (size_t)bh * cS * cS;
#pragma unroll
    for (int m = 0; m < 4; ++m)
#pragma unroll
        for (int n = 0; n < 4; ++n)
#pragma unroll
            for (int r = 0; r < 4; ++r)
                Crow[(size_t)(bm + wr + m * 16 + hi16 * 4 + r) * cS + bn + wc + n * 16 + r15]
                    = acc[m][n][r];
}

// ---------------------------------------------------------------------------
// row softmax over scores, in-place rewrite as split-bf16 P.
// Row memory (4096B): fp32 scores -> u16 hi at [k], u16 lo at [1024+k].
// blockIdx.x = q, blockIdx.y = bh
// ---------------------------------------------------------------------------
__global__ __launch_bounds__(256) void softmax_kernel(float* __restrict__ Sc,
                                                      const int* __restrict__ tlen,
                                                      int win) {
    const int q = blockIdx.x, bh = blockIdx.y, b = bh / cH;
    float* row = Sc + ((size_t)bh * cS + q) * cS;
    u16* rowh = (u16*)row;
    const int tid = threadIdx.x;
    const int tl = tlen[b];
    const int kmax = min(q, tl - 1);
    const int kmin = (win > 0) ? max(0, q - win + 1) : 0;

    float v[4];
    float m = -1e30f;
#pragma unroll
    for (int j = 0; j < 4; ++j) {
        const int k = tid + j * 256;
        const bool ok = (k >= kmin && k <= kmax);
        v[j] = ok ? row[k] : -1e30f;
        m = fmaxf(m, v[j]);
    }
    for (int o = 32; o >= 1; o >>= 1) m = fmaxf(m, __shfl_xor(m, o));
    __shared__ float rb[8];
    if ((tid & 63) == 0) rb[tid >> 6] = m;
    __syncthreads();
    m = fmaxf(fmaxf(rb[0], rb[1]), fmaxf(rb[2], rb[3]));

    float e[4];
    float s = 0.f;
#pragma unroll
    for (int j = 0; j < 4; ++j) {
        const int k = tid + j * 256;
        const bool ok = (k >= kmin && k <= kmax);
        e[j] = ok ? expf(v[j] - m) : 0.f;
        s += e[j];
    }
    for (int o = 32; o >= 1; o >>= 1) s += __shfl_xor(s, o);
    __shared__ float sb[4];
    if ((tid & 63) == 0) sb[tid >> 6] = s;
    __syncthreads();
    s = sb[0] + sb[1] + sb[2] + sb[3];
    const float inv = 1.f / s;
    __syncthreads();   // all fp32 reads complete before u16 overwrite
#pragma unroll
    for (int j = 0; j < 4; ++j) {
        const int k = tid + j * 256;
        u16 hh, ll;
        splitbf(e[j] * inv, hh, ll);
        rowh[k] = hh;
        rowh[1024 + k] = ll;
    }
}

// ---------------------------------------------------------------------------
// batched PV: O[b,q,h*HDIM+d] (split-bf16) = P[bh] @ V[b,kh].
// P: u16 rows of 2048 (hi [0,1024), lo [1024,2048)), Vt: [B*KVH, HDIM, S] split.
// ---------------------------------------------------------------------------
__global__ __launch_bounds__(256) void pv_kernel(const u16* __restrict__ P,
                                                 const u16* __restrict__ Vt, int vps,
                                                 u16* __restrict__ O, int ops,
                                                 int HDIM, int KVH, int win) {
    const int bh = blockIdx.z;
    const int b = bh / cH, h = bh % cH;
    const int kh = h / (cH / KVH);
    const int bm = blockIdx.y * 128;   // q tile
    const int bn = blockIdx.x * 128;   // d tile

    __shared__ u16 As[2][128 * 32];
    __shared__ u16 Bs[2][128 * 32];
    const int tid = threadIdx.x;
    const int lane = tid & 63;
    const int w = tid >> 6;
    const int wr = (w >> 1) * 64, wc = (w & 1) * 64;
    const int r15 = lane & 15, hi16 = lane >> 4;

    const u16* Ap = P + (size_t)bh * cS * 2048;
    const u16* Bv = Vt + ((size_t)b * KVH + kh) * HDIM * cS;

    f32x4 acc[4][4];
#pragma unroll
    for (int m = 0; m < 4; ++m)
#pragma unroll
        for (int n = 0; n < 4; ++n) acc[m][n] = (f32x4){0.f, 0.f, 0.f, 0.f};

    const int c0 = tid, c1 = tid + 256;
    const int ar0 = c0 >> 2, ak0 = (c0 & 3) * 8;
    const int ar1 = c1 >> 2, ak1 = (c1 & 3) * 8;

    const int klo = (win > 0) ? (max(0, bm - win + 1) & ~31) : 0;
    const int khi = min(bm + 128, cS);

    for (int k0 = klo; k0 < khi; k0 += 32) {
        uint4 v0 = *(const uint4*)&Ap[(size_t)(bm + ar0) * 2048 + k0 + ak0];
        uint4 v1 = *(const uint4*)&Ap[(size_t)(bm + ar1) * 2048 + k0 + ak1];
        uint4 v2 = *(const uint4*)&Ap[(size_t)(bm + ar0) * 2048 + 1024 + k0 + ak0];
        uint4 v3 = *(const uint4*)&Ap[(size_t)(bm + ar1) * 2048 + 1024 + k0 + ak1];
        uint4 v4 = *(const uint4*)&Bv[(size_t)(bn + ar0) * cS + k0 + ak0];
        uint4 v5 = *(const uint4*)&Bv[(size_t)(bn + ar1) * cS + k0 + ak1];
        uint4 v6 = *(const uint4*)&Bv[(size_t)vps + (size_t)(bn + ar0) * cS + k0 + ak0];
        uint4 v7 = *(const uint4*)&Bv[(size_t)vps + (size_t)(bn + ar1) * cS + k0 + ak1];
        __syncthreads();
        *(uint4*)&As[0][c0 * 8] = v0;
        *(uint4*)&As[0][c1 * 8] = v1;
        *(uint4*)&As[1][c0 * 8] = v2;
        *(uint4*)&As[1][c1 * 8] = v3;
        *(uint4*)&Bs[0][c0 * 8] = v4;
        *(uint4*)&Bs[0][c1 * 8] = v5;
        *(uint4*)&Bs[1][c0 * 8] = v6;
        *(uint4*)&Bs[1][c1 * 8] = v7;
        __syncthreads();
        bf16x8 ah[4], al[4], bh4[4], bl4[4];
#pragma unroll
        for (int m = 0; m < 4; ++m) {
            ah[m] = *(const bf16x8*)&As[0][(wr + m * 16 + r15) * 32 + hi16 * 8];
            al[m] = *(const bf16x8*)&As[1][(wr + m * 16 + r15) * 32 + hi16 * 8];
        }
#pragma unroll
        for (int n = 0; n < 4; ++n) {
            bh4[n] = *(const bf16x8*)&Bs[0][(wc + n * 16 + r15) * 32 + hi16 * 8];
            bl4[n] = *(const bf16x8*)&Bs[1][(wc + n * 16 + r15) * 32 + hi16 * 8];
        }
#pragma unroll
        for (int m = 0; m < 4; ++m)
#pragma unroll
            for (int n = 0; n < 4; ++n) {
                acc[m][n] = __builtin_amdgcn_mfma_f32_16x16x32_bf16(ah[m], bl4[n], acc[m][n], 0, 0, 0);
                acc[m][n] = __builtin_amdgcn_mfma_f32_16x16x32_bf16(al[m], bh4[n], acc[m][n], 0, 0, 0);
                acc[m][n] = __builtin_amdgcn_mfma_f32_16x16x32_bf16(ah[m], bh4[n], acc[m][n], 0, 0, 0);
            }
    }
    const int ldo = cH * HDIM;
#pragma unroll
    for (int m = 0; m < 4; ++m)
#pragma unroll
        for (int n = 0; n < 4; ++n)
#pragma unroll
            for (int r = 0; r < 4; ++r) {
                const int q = bm + wr + m * 16 + hi16 * 4 + r;
                const int d = bn + wc + n * 16 + r15;
                const size_t idx = (size_t)(b * cS + q) * ldo + h * HDIM + d;
                u16 hh, ll;
                splitbf(acc[m][n][r], hh, ll);
                O[idx] = hh;
                O[(size_t)ops + idx] = ll;
            }
}

// ---------------------------------------------------------------------------
// gated FFN elementwise on split-bf16: out = gelu_tanh(g) * u  (4/thread)
// ---------------------------------------------------------------------------
__global__ void gelumul_kernel(const u16* __restrict__ g, const u16* __restrict__ u,
                               u16* __restrict__ out, int n, int ps) {
    const int i = blockIdx.x * blockDim.x + threadIdx.x;
    if (i * 4 >= n) return;
    const uint2 gh = *(const uint2*)&g[(size_t)i * 4];
    const uint2 gl = *(const uint2*)&g[(size_t)ps + (size_t)i * 4];
    const uint2 uh = *(const uint2*)&u[(size_t)i * 4];
    const uint2 ul = *(const uint2*)&u[(size_t)ps + (size_t)i * 4];
    auto gelu = [](float v) {
        const float t = tanhf(0.7978845608028654f * (v + 0.044715f * v * v * v));
        return 0.5f * v * (1.f + t);
    };
    float gv[4] = { bf2f((u16)(gh.x & 0xffff)) + bf2f((u16)(gl.x & 0xffff)),
                    bf2f((u16)(gh.x >> 16))    + bf2f((u16)(gl.x >> 16)),
                    bf2f((u16)(gh.y & 0xffff)) + bf2f((u16)(gl.y & 0xffff)),
                    bf2f((u16)(gh.y >> 16))    + bf2f((u16)(gl.y >> 16)) };
    float uv[4] = { bf2f((u16)(uh.x & 0xffff)) + bf2f((u16)(ul.x & 0xffff)),
                    bf2f((u16)(uh.x >> 16))    + bf2f((u16)(ul.x >> 16)),
                    bf2f((u16)(uh.y & 0xffff)) + bf2f((u16)(ul.y & 0xffff)),
                    bf2f((u16)(uh.y >> 16))    + bf2f((u16)(ul.y >> 16)) };
    u16 h[4], l[4];
#pragma unroll
    for (int j = 0; j < 4; ++j) splitbf(gelu(gv[j]) * uv[j], h[j], l[j]);
    uint2 oh, ol;
    oh.x = (unsigned)h[0] | ((unsigned)h[1] << 16);
    oh.y = (unsigned)h[2] | ((unsigned)h[3] << 16);
    ol.x = (unsigned)l[0] | ((unsigned)l[1] << 16);
    ol.y = (unsigned)l[2] | ((unsigned)l[3] << 16);
    *(uint2*)&out[(size_t)i * 4] = oh;
    *(uint2*)&out[(size_t)ps + (size_t)i * 4] = ol;
}

// ---------------------------------------------------------------------------
extern "C" void kernel_launch(void* const* d_in, const int* in_sizes, int n_in,
                              void* d_out, int out_size, void* d_ws, size_t ws_size,
                              hipStream_t stream) {
    (void)in_sizes; (void)n_in; (void)out_size; (void)ws_size;
    const int*   tokens = (const int*)  d_in[0];
    const int*   tlen   = (const int*)  d_in[1];
    const float* embed  = (const float*)d_in[2];
    const float* norm_w = (const float*)d_in[3];
    const float* s_wq   = (const float*)d_in[4];
    const float* s_wk   = (const float*)d_in[5];
    const float* s_wv   = (const float*)d_in[6];
    const float* s_wo   = (const float*)d_in[7];
    const float* s_qn   = (const float*)d_in[8];
    const float* s_kn   = (const float*)d_in[9];
    const float* s_wg   = (const float*)d_in[10];
    const float* s_wu   = (const float*)d_in[11];
    const float* s_wd   = (const float*)d_in[12];
    const float* s_ln1  = (const float*)d_in[13];
    const float* s_ln2  = (const float*)d_in[14];
    const float* s_ln3  = (const float*)d_in[15];
    const float* s_ln4  = (const float*)d_in[16];
    const float* s_scal = (const float*)d_in[17];
    const float* g_wq   = (const float*)d_in[18];
    const float* g_wk   = (const float*)d_in[19];
    const float* g_wo   = (const float*)d_in[20];
    const float* g_qn   = (const float*)d_in[21];
    const float* g_kn   = (const float*)d_in[22];
    const float* g_wg   = (const float*)d_in[23];
    const float* g_wu   = (const float*)d_in[24];
    const float* g_wd   = (const float*)d_in[25];
    const float* g_ln1  = (const float*)d_in[26];
    const float* g_ln2  = (const float*)d_in[27];
    const float* g_ln3  = (const float*)d_in[28];
    const float* g_ln4  = (const float*)d_in[29];
    const float* g_scal = (const float*)d_in[30];

    // workspace (160 MiB peak):
    //   [0,16)    x       fp32 residual
    //   [16,32)   ab      split-bf16 normed activations | attn: Kb split-bf16
    //   [32,48)   r0      fp32 k / oproj-out / ffn accumulator
    //   [48,64)   r1      fp32 v
    //   [32,96)   scores  fp32 [16,1024,1024] (after K/V fp32 dead) -> P in place
    //   [64,96)   bb      split-bf16 weight panels (after P dead for wo)
    //   [96,128)  t0      fp32 q | attn: Vt @[96,112) after q dead | bf16 gate
    //   [128,160) t1      split-bf16 Qb -> O (PV overwrites) | bf16 up chunk
    char* w8 = (char*)d_ws;
    float* x   = (float*)(w8);
    u16*   ab  = (u16*)(w8 + 16 * MB);
    u16*   Kb  = (u16*)(w8 + 16 * MB);
    float* r0  = (float*)(w8 + 32 * MB);
    float* scores = (float*)(w8 + 32 * MB);
    u16*   Pb  = (u16*)(w8 + 32 * MB);
    float* r1  = (float*)(w8 + 48 * MB);
    u16*   bb  = (u16*)(w8 + 64 * MB);
    float* t0f = (float*)(w8 + 96 * MB);
    u16*   Vt  = (u16*)(w8 + 96 * MB);
    u16*   t0b = (u16*)(w8 + 96 * MB);
    u16*   t1b = (u16*)(w8 + 128 * MB);

    constexpr int PS_AB = cM * cD;          // 4,194,304
    constexpr int CF    = 4096;             // FFN N-chunk
    constexpr int CHV   = 3200;             // logits N-chunk (10 chunks)

    auto tcast = [&](const float* in, u16* outp, int K, int N, int ldin, int ps) {
        tcast_kernel<<<dim3(N / 32, K / 32), 256, 0, stream>>>(in, outp, K, N, ldin, ps);
    };
    auto gemmF = [&](const u16* A, const u16* Bt, float* C, int M, int N, int K,
                     int ldc, int aps, int bps, bool accum) {
        if (accum)
            gemm_split<false, true><<<dim3(N / 128, M / 128), 256, 0, stream>>>(
                A, Bt, C, M, N, K, ldc, aps, bps, 0);
        else
            gemm_split<false, false><<<dim3(N / 128, M / 128), 256, 0, stream>>>(
                A, Bt, C, M, N, K, ldc, aps, bps, 0);
    };
    auto gemmB = [&](const u16* A, const u16* Bt, u16* C, int M, int N, int K,
                     int ldc, int aps, int bps, int cps) {
        gemm_split<true, false><<<dim3(N / 128, M / 128), 256, 0, stream>>>(
            A, Bt, C, M, N, K, ldc, aps, bps, cps);
    };

    // attention via MFMA: Q fp32 in t0f, K fp32 in r0, V fp32 in r1
    auto attention = [&](int HDIM, int KVH, int win) {
        const int qn = cM * cH * HDIM;
        const int kn = cM * KVH * HDIM;
        cast_kernel<<<(qn / 4 + 255) / 256, 256, 0, stream>>>(t0f, t1b, qn, qn);   // Qb
        cast_kernel<<<(kn / 4 + 255) / 256, 256, 0, stream>>>(r0, Kb, kn, kn);     // Kb
        vtrans_kernel<<<dim3(HDIM / 32, cS / 32, cB * KVH), 256, 0, stream>>>(
            r1, Vt, HDIM, KVH, kn);                                                // Vt
        qk_kernel<<<dim3(cS / 128, cS / 128, cB * cH), 256, 0, stream>>>(
            t1b, qn, Kb, kn, scores, HDIM, KVH, win);
        softmax_kernel<<<dim3(cS, cB * cH), 256, 0, stream>>>(scores, tlen, win);
        pv_kernel<<<dim3(HDIM / 128, cS / 128, cB * cH), 256, 0, stream>>>(
            Pb, Vt, kn, t1b, qn, HDIM, KVH, win);                                  // O -> t1b
    };

    embed_kernel<<<cM, 256, 0, stream>>>(tokens, embed, x);

    // ================= block 1: sliding-window =================
    rms_bf16_kernel<<<cM, 256, 0, stream>>>(x, s_ln1, ab, cD, PS_AB);
    tcast(s_wq, bb, cD, cH * cHD, cH * cHD, cD * cH * cHD);
    gemmF(ab, bb, t0f, cM, cH * cHD, cD, cH * cHD, PS_AB, cD * cH * cHD, false);
    tcast(s_wk, bb, cD, cKV * cHD, cKV * cHD, cD * cKV * cHD);
    gemmF(ab, bb, r0, cM, cKV * cHD, cD, cKV * cHD, PS_AB, cD * cKV * cHD, false);
    tcast(s_wv, bb, cD, cKV * cHD, cKV * cHD, cD * cKV * cHD);
    gemmF(ab, bb, r1, cM, cKV * cHD, cD, cKV * cHD, PS_AB, cD * cKV * cHD, false);
    rms_kernel<<<cM * cKV, 256, 0, stream>>>(r1, nullptr, r1, cHD);     // xv = rms_ns(h@wv)
    rms_kernel<<<cM * cH, 256, 0, stream>>>(t0f, s_qn, t0f, cHD);
    rms_kernel<<<cM * cKV, 256, 0, stream>>>(r0, s_kn, r0, cHD);
    rope_kernel<<<cM * cH, 128, 0, stream>>>(t0f, cH, cHD, cHD, 10000.f);
    rope_kernel<<<cM * cKV, 128, 0, stream>>>(r0, cKV, cHD, cHD, 10000.f);
    attention(cHD, cKV, cWIN);
    tcast(s_wo, bb, cH * cHD, cD, cD, cH * cHD * cD);
    gemmF(t1b, bb, r0, cM, cD, cH * cHD, cD, cM * cH * cHD, cH * cHD * cD, false);
    rms_add_kernel<<<cM, 256, 0, stream>>>(x, r0, s_ln2, nullptr, x, cD);
    rms_bf16_kernel<<<cM, 256, 0, stream>>>(x, s_ln3, ab, cD, PS_AB);
    for (int c = 0; c < cF / CF; ++c) {
        tcast(s_wg + (size_t)c * CF, bb, cD, CF, cF, cD * CF);
        gemmB(ab, bb, t0b, cM, CF, cD, CF, PS_AB, cD * CF, cM * CF);
        tcast(s_wu + (size_t)c * CF, bb, cD, CF, cF, cD * CF);
        gemmB(ab, bb, t1b, cM, CF, cD, CF, PS_AB, cD * CF, cM * CF);
        gelumul_kernel<<<(cM * CF / 4 + 255) / 256, 256, 0, stream>>>(t0b, t1b, t0b,
                                                                     cM * CF, cM * CF);
        tcast(s_wd + (size_t)c * CF * cD, bb, CF, cD, cD, CF * cD);
        gemmF(t0b, bb, r0, cM, cD, CF, cD, cM * CF, CF * cD, c > 0);
    }
    rms_add_kernel<<<cM, 256, 0, stream>>>(x, r0, s_ln4, s_scal, x, cD);

    // ================= block 2: global =================
    rms_bf16_kernel<<<cM, 256, 0, stream>>>(x, g_ln1, ab, cD, PS_AB);
    tcast(g_wq, bb, cD, cH * cGHD, cH * cGHD, cD * cH * cGHD);
    gemmF(ab, bb, t0f, cM, cH * cGHD, cD, cH * cGHD, PS_AB, cD * cH * cGHD, false);
    tcast(g_wk, bb, cD, cGKV * cGHD, cGKV * cGHD, cD * cGKV * cGHD);
    gemmF(ab, bb, r0, cM, cGKV * cGHD, cD, cGKV * cGHD, PS_AB, cD * cGKV * cGHD, false);
    rms_kernel<<<cM * cGKV, 256, 0, stream>>>(r0, nullptr, r1, cGHD);   // xv = rms_ns(raw xk)
    rms_kernel<<<cM * cH, 256, 0, stream>>>(t0f, g_qn, t0f, cGHD);
    rms_kernel<<<cM * cGKV, 256, 0, stream>>>(r0, g_kn, r0, cGHD);
    rope_kernel<<<cM * cH, 64, 0, stream>>>(t0f, cH, cGHD, cROT, 1000000.f);
    rope_kernel<<<cM * cGKV, 64, 0, stream>>>(r0, cGKV, cGHD, cROT, 1000000.f);
    attention(cGHD, cGKV, 0);
    tcast(g_wo, bb, cH * cGHD, cD, cD, cH * cGHD * cD);
    gemmF(t1b, bb, r0, cM, cD, cH * cGHD, cD, cM * cH * cGHD, cH * cGHD * cD, false);
    rms_add_kernel<<<cM, 256, 0, stream>>>(x, r0, g_ln2, nullptr, x, cD);
    rms_bf16_kernel<<<cM, 256, 0, stream>>>(x, g_ln3, ab, cD, PS_AB);
    for (int c = 0; c < cF / CF; ++c) {
        tcast(g_wg + (size_t)c * CF, bb, cD, CF, cF, cD * CF);
        gemmB(ab, bb, t0b, cM, CF, cD, CF, PS_AB, cD * CF, cM * CF);
        tcast(g_wu + (size_t)c * CF, bb, cD, CF, cF, cD * CF);
        gemmB(ab, bb, t1b, cM, CF, cD, CF, PS_AB, cD * CF, cM * CF);
        gelumul_kernel<<<(cM * CF / 4 + 255) / 256, 256, 0, stream>>>(t0b, t1b, t0b,
                                                                     cM * CF, cM * CF);
        tcast(g_wd + (size_t)c * CF * cD, bb, CF, cD, cD, CF * cD);
        gemmF(t0b, bb, r0, cM, cD, CF, cD, cM * CF, CF * cD, c > 0);
    }
    rms_add_kernel<<<cM, 256, 0, stream>>>(x, r0, g_ln4, g_scal, x, cD);

    // ================= final norm + logits (chunked over V) =================
    rms_bf16_kernel<<<cM, 256, 0, stream>>>(x, norm_w, ab, cD, PS_AB);
    for (int c = 0; c < cV / CHV; ++c) {
        cast_kernel<<<(CHV * cD / 4 + 255) / 256, 256, 0, stream>>>(
            embed + (size_t)c * CHV * cD, bb, CHV * cD, CHV * cD);
        gemmF(ab, bb, (float*)d_out + (size_t)c * CHV, cM, CHV, cD, cV,
              PS_AB, CHV * cD, false);
    }
}

// Round 5
// 4113.671 us; speedup vs baseline: 3.8769x; 1.0374x over previous
//
#include <hip/hip_runtime.h>
#include <math.h>

typedef unsigned short u16;
typedef __attribute__((ext_vector_type(8))) short bf16x8;
typedef __attribute__((ext_vector_type(4))) float f32x4;

// ---- problem constants ----
constexpr int cB   = 2;
constexpr int cS   = 1024;
constexpr int cD   = 2048;
constexpr int cH   = 8;
constexpr int cHD  = 256;
constexpr int cKV  = 4;
constexpr int cGHD = 512;
constexpr int cGKV = 4;
constexpr int cROT = 128;
constexpr int cF   = 8192;
constexpr int cV   = 32000;
constexpr int cWIN = 512;
constexpr int cM   = cB * cS;   // 2048 token rows
constexpr float cEPS = 1e-6f;
constexpr size_t MB = 1024 * 1024;

__device__ inline u16 f2bf(float x) {
    unsigned u = __float_as_uint(x);
    u += 0x7fff + ((u >> 16) & 1);     // RNE
    return (u16)(u >> 16);
}
__device__ inline float bf2f(u16 v) { return __uint_as_float(((unsigned)v) << 16); }
// split: hi = bf16(v), lo = bf16(v - hi)
__device__ inline void splitbf(float v, u16& h, u16& l) {
    h = f2bf(v);
    l = f2bf(v - bf2f(h));
}
// swizzled LDS u16-index: row-major [128][32] u16, 16B chunks XOR'd by (row>>1)&3
// -> 2-way max bank aliasing on both ds_read_b128 frag reads and staging writes.
__device__ inline int swz16(int row, int chunk) {
    return row * 32 + ((chunk ^ ((row >> 1) & 3)) << 3);
}

// ---------------------------------------------------------------------------
// embed lookup * sqrt(D)
// ---------------------------------------------------------------------------
__global__ void embed_kernel(const int* __restrict__ tok,
                             const float* __restrict__ emb,
                             float* __restrict__ out) {
    const int row = blockIdx.x;
    const int t = tok[row];
    const float* e = emb + (size_t)t * cD;
    float* o = out + (size_t)row * cD;
    const float sc = sqrtf((float)cD);
    for (int d = threadIdx.x; d < cD; d += blockDim.x) o[d] = e[d] * sc;
}

// ---------------------------------------------------------------------------
// row RMS norm fp32->fp32
// ---------------------------------------------------------------------------
__global__ void rms_kernel(const float* __restrict__ x,
                           const float* __restrict__ w,
                           float* __restrict__ out, int dim) {
    const int row = blockIdx.x;
    const float* xr = x + (size_t)row * dim;
    float* orow = out + (size_t)row * dim;
    float ss = 0.f;
    for (int d = threadIdx.x; d < dim; d += blockDim.x) { float v = xr[d]; ss += v * v; }
    for (int o = 32; o >= 1; o >>= 1) ss += __shfl_xor(ss, o);
    __shared__ float rb[8];
    if ((threadIdx.x & 63) == 0) rb[threadIdx.x >> 6] = ss;
    __syncthreads();
    ss = rb[0] + rb[1] + rb[2] + rb[3];
    const float r = rsqrtf(ss / dim + cEPS);
    for (int d = threadIdx.x; d < dim; d += blockDim.x)
        orow[d] = xr[d] * r * (w ? w[d] : 1.f);
}

// row RMS norm fp32 -> split-bf16 (two planes, lo at +ps)
__global__ void rms_bf16_kernel(const float* __restrict__ x,
                                const float* __restrict__ w,
                                u16* __restrict__ out, int dim, int ps) {
    const int row = blockIdx.x;
    const float* xr = x + (size_t)row * dim;
    const size_t base = (size_t)row * dim;
    float ss = 0.f;
    for (int d = threadIdx.x; d < dim; d += blockDim.x) { float v = xr[d]; ss += v * v; }
    for (int o = 32; o >= 1; o >>= 1) ss += __shfl_xor(ss, o);
    __shared__ float rb[8];
    if ((threadIdx.x & 63) == 0) rb[threadIdx.x >> 6] = ss;
    __syncthreads();
    ss = rb[0] + rb[1] + rb[2] + rb[3];
    const float r = rsqrtf(ss / dim + cEPS);
    for (int d = threadIdx.x; d < dim; d += blockDim.x) {
        u16 h, l;
        splitbf(xr[d] * r * (w ? w[d] : 1.f), h, l);
        out[base + d] = h;
        out[(size_t)ps + base + d] = l;
    }
}

// out = (res + x * rsqrt(mean(x^2)+eps) * w) * (scal or 1)   (out may alias res)
__global__ void rms_add_kernel(const float* __restrict__ res,
                               const float* __restrict__ x,
                               const float* __restrict__ w,
                               const float* __restrict__ scal,
                               float* __restrict__ out, int dim) {
    const int row = blockIdx.x;
    const float* xr = x + (size_t)row * dim;
    const float* rr = res + (size_t)row * dim;
    float* orow = out + (size_t)row * dim;
    float ss = 0.f;
    for (int d = threadIdx.x; d < dim; d += blockDim.x) { float v = xr[d]; ss += v * v; }
    for (int o = 32; o >= 1; o >>= 1) ss += __shfl_xor(ss, o);
    __shared__ float rb[8];
    if ((threadIdx.x & 63) == 0) rb[threadIdx.x >> 6] = ss;
    __syncthreads();
    ss = rb[0] + rb[1] + rb[2] + rb[3];
    const float r = rsqrtf(ss / dim + cEPS);
    const float sc = scal ? *scal : 1.f;
    for (int d = threadIdx.x; d < dim; d += blockDim.x)
        orow[d] = (rr[d] + xr[d] * r * w[d]) * sc;
}

// ---------------------------------------------------------------------------
// RoPE in place on first `rot` dims of each head row (fp32).
// ---------------------------------------------------------------------------
__global__ void rope_kernel(float* __restrict__ x, int NH, int HDIM, int rot, float theta) {
    const int row = blockIdx.x;
    const int s = (row / NH) % cS;
    float* xr = x + (size_t)row * HDIM;
    const int half = rot >> 1;
    for (int i = threadIdx.x; i < half; i += blockDim.x) {
        const float inv = powf(theta, -(2.f * i) / (float)rot);
        const float ang = (float)s * inv;
        const float c = cosf(ang), sn = sinf(ang);
        const float x1 = xr[2 * i], x2 = xr[2 * i + 1];
        xr[2 * i]     = x1 * c - x2 * sn;
        xr[2 * i + 1] = x1 * sn + x2 * c;
    }
}

// ---------------------------------------------------------------------------
// fp32 [K][N-chunk] (row stride ldin) -> split-bf16 [N][K] (lo plane at +ps)
// ---------------------------------------------------------------------------
__global__ __launch_bounds__(256) void tcast_kernel(const float* __restrict__ in,
                                                    u16* __restrict__ out,
                                                    int K, int N, int ldin, int ps) {
    __shared__ float t[32][33];
    const int kt = blockIdx.y * 32, nt = blockIdx.x * 32;
    const int tx = threadIdx.x & 31, ty = threadIdx.x >> 5;   // ty 0..7
#pragma unroll
    for (int j = 0; j < 4; ++j)
        t[ty + j * 8][tx] = in[(size_t)(kt + ty + j * 8) * ldin + nt + tx];
    __syncthreads();
#pragma unroll
    for (int j = 0; j < 4; ++j) {
        u16 h, l;
        splitbf(t[tx][ty + j * 8], h, l);
        const size_t idx = (size_t)(nt + ty + j * 8) * K + kt + tx;
        out[idx] = h;
        out[(size_t)ps + idx] = l;
    }
}

// fp32 -> split-bf16 elementwise (4 per thread)
__global__ void cast_kernel(const float* __restrict__ in, u16* __restrict__ out,
                            int n, int ps) {
    const int i = blockIdx.x * blockDim.x + threadIdx.x;
    if (i * 4 >= n) return;
    const float4 v = *(const float4*)&in[(size_t)i * 4];
    u16 h[4], l[4];
    splitbf(v.x, h[0], l[0]); splitbf(v.y, h[1], l[1]);
    splitbf(v.z, h[2], l[2]); splitbf(v.w, h[3], l[3]);
    uint2 oh, ol;
    oh.x = (unsigned)h[0] | ((unsigned)h[1] << 16);
    oh.y = (unsigned)h[2] | ((unsigned)h[3] << 16);
    ol.x = (unsigned)l[0] | ((unsigned)l[1] << 16);
    ol.y = (unsigned)l[2] | ((unsigned)l[3] << 16);
    *(uint2*)&out[(size_t)i * 4] = oh;
    *(uint2*)&out[(size_t)ps + (size_t)i * 4] = ol;
}

// V fp32 [B,S,KVH,HDIM] -> Vt split-bf16 [B*KVH, HDIM, S] (lo at +vps)
__global__ __launch_bounds__(256) void vtrans_kernel(const float* __restrict__ V,
                                                     u16* __restrict__ Vt,
                                                     int HDIM, int KVH, int vps) {
    __shared__ float t[32][33];
    const int bk = blockIdx.z;
    const int b = bk / KVH, kh = bk % KVH;
    const int st = blockIdx.y * 32, dt = blockIdx.x * 32;
    const int tx = threadIdx.x & 31, ty = threadIdx.x >> 5;
#pragma unroll
    for (int j = 0; j < 4; ++j)
        t[ty + j * 8][tx] = V[((size_t)(b * cS + st + ty + j * 8) * KVH + kh) * HDIM + dt + tx];
    __syncthreads();
#pragma unroll
    for (int j = 0; j < 4; ++j) {
        u16 h, l;
        splitbf(t[tx][ty + j * 8], h, l);
        const size_t idx = ((size_t)bk * HDIM + dt + ty + j * 8) * cS + st + tx;
        Vt[idx] = h;
        Vt[(size_t)vps + idx] = l;
    }
}

// ---------------------------------------------------------------------------
// split-bf16 MFMA GEMM: C[M,N] = (A_hi+A_lo)[M,K] @ (B_hi+B_lo)[N,K]^T
// (drops lo*lo). 128x128 tile, BK=32, 256 threads, 3 MFMAs per frag pair.
// Swizzled LDS (swz16) on write+read.
// ---------------------------------------------------------------------------
template<bool BF16_OUT, bool ACCUM>
__global__ __launch_bounds__(256) void gemm_split(const u16* __restrict__ A,
                                                  const u16* __restrict__ Bt,
                                                  void* __restrict__ Cout,
                                                  int M, int N, int K, int ldc,
                                                  int aps, int bps, int cps) {
    __shared__ u16 As[2][128 * 32];
    __shared__ u16 Bs[2][128 * 32];
    const int bm = blockIdx.y * 128;
    const int bn = blockIdx.x * 128;
    const int tid = threadIdx.x;
    const int lane = tid & 63;
    const int w = tid >> 6;
    const int wr = (w >> 1) * 64, wc = (w & 1) * 64;
    const int r15 = lane & 15, hi16 = lane >> 4;

    f32x4 acc[4][4];
#pragma unroll
    for (int m = 0; m < 4; ++m)
#pragma unroll
        for (int n = 0; n < 4; ++n) acc[m][n] = (f32x4){0.f, 0.f, 0.f, 0.f};

    const int c0 = tid, c1 = tid + 256;
    const int ar0 = c0 >> 2, ak0 = (c0 & 3) * 8;
    const int ar1 = c1 >> 2, ak1 = (c1 & 3) * 8;
    const int w0 = swz16(ar0, c0 & 3), w1 = swz16(ar1, c1 & 3);
    const u16* Al = A + aps;
    const u16* Bl = Bt + bps;

    for (int k0 = 0; k0 < K; k0 += 32) {
        uint4 v0 = *(const uint4*)&A [(size_t)(bm + ar0) * K + k0 + ak0];
        uint4 v1 = *(const uint4*)&A [(size_t)(bm + ar1) * K + k0 + ak1];
        uint4 v2 = *(const uint4*)&Al[(size_t)(bm + ar0) * K + k0 + ak0];
        uint4 v3 = *(const uint4*)&Al[(size_t)(bm + ar1) * K + k0 + ak1];
        uint4 v4 = *(const uint4*)&Bt[(size_t)(bn + ar0) * K + k0 + ak0];
        uint4 v5 = *(const uint4*)&Bt[(size_t)(bn + ar1) * K + k0 + ak1];
        uint4 v6 = *(const uint4*)&Bl[(size_t)(bn + ar0) * K + k0 + ak0];
        uint4 v7 = *(const uint4*)&Bl[(size_t)(bn + ar1) * K + k0 + ak1];
        __syncthreads();
        *(uint4*)&As[0][w0] = v0;
        *(uint4*)&As[0][w1] = v1;
        *(uint4*)&As[1][w0] = v2;
        *(uint4*)&As[1][w1] = v3;
        *(uint4*)&Bs[0][w0] = v4;
        *(uint4*)&Bs[0][w1] = v5;
        *(uint4*)&Bs[1][w0] = v6;
        *(uint4*)&Bs[1][w1] = v7;
        __syncthreads();
        bf16x8 ah[4], al[4], bh[4], bl[4];
#pragma unroll
        for (int m = 0; m < 4; ++m) {
            const int o = swz16(wr + m * 16 + r15, hi16);
            ah[m] = *(const bf16x8*)&As[0][o];
            al[m] = *(const bf16x8*)&As[1][o];
        }
#pragma unroll
        for (int n = 0; n < 4; ++n) {
            const int o = swz16(wc + n * 16 + r15, hi16);
            bh[n] = *(const bf16x8*)&Bs[0][o];
            bl[n] = *(const bf16x8*)&Bs[1][o];
        }
#pragma unroll
        for (int m = 0; m < 4; ++m)
#pragma unroll
            for (int n = 0; n < 4; ++n) {
                acc[m][n] = __builtin_amdgcn_mfma_f32_16x16x32_bf16(ah[m], bl[n], acc[m][n], 0, 0, 0);
                acc[m][n] = __builtin_amdgcn_mfma_f32_16x16x32_bf16(al[m], bh[n], acc[m][n], 0, 0, 0);
                acc[m][n] = __builtin_amdgcn_mfma_f32_16x16x32_bf16(ah[m], bh[n], acc[m][n], 0, 0, 0);
            }
    }
#pragma unroll
    for (int m = 0; m < 4; ++m)
#pragma unroll
        for (int n = 0; n < 4; ++n)
#pragma unroll
            for (int r = 0; r < 4; ++r) {
                const int row = bm + wr + m * 16 + hi16 * 4 + r;
                const int col = bn + wc + n * 16 + r15;
                float v = acc[m][n][r];
                if (BF16_OUT) {
                    u16 h, l;
                    splitbf(v, h, l);
                    ((u16*)Cout)[(size_t)row * ldc + col] = h;
                    ((u16*)Cout)[(size_t)cps + (size_t)row * ldc + col] = l;
                } else {
                    float* cp = (float*)Cout + (size_t)row * ldc + col;
                    if (ACCUM) v += *cp;
                    *cp = v;
                }
            }
}

// ---------------------------------------------------------------------------
// logits GEMM: C[M,N] fp32 = (A_hi+A_lo)[M,K] @ Bf[N,K]^T, Bf fp32 read
// directly (embed) and truncation-split to hi/lo bf16 during LDS staging.
// ---------------------------------------------------------------------------
__global__ __launch_bounds__(256) void gemm_absplit_bfp32(const u16* __restrict__ A,
                                                          int aps,
                                                          const float* __restrict__ Bf,
                                                          float* __restrict__ Cout,
                                                          int M, int N, int K, int ldc) {
    __shared__ u16 As[2][128 * 32];
    __shared__ u16 Bs[2][128 * 32];
    const int bm = blockIdx.y * 128;
    const int bn = blockIdx.x * 128;
    const int tid = threadIdx.x;
    const int lane = tid & 63;
    const int w = tid >> 6;
    const int wr = (w >> 1) * 64, wc = (w & 1) * 64;
    const int r15 = lane & 15, hi16 = lane >> 4;

    f32x4 acc[4][4];
#pragma unroll
    for (int m = 0; m < 4; ++m)
#pragma unroll
        for (int n = 0; n < 4; ++n) acc[m][n] = (f32x4){0.f, 0.f, 0.f, 0.f};

    const int c0 = tid, c1 = tid + 256;
    const int ar0 = c0 >> 2, ak0 = (c0 & 3) * 8;
    const int ar1 = c1 >> 2, ak1 = (c1 & 3) * 8;
    const int w0 = swz16(ar0, c0 & 3), w1 = swz16(ar1, c1 & 3);
    const u16* Al = A + aps;

    for (int k0 = 0; k0 < K; k0 += 32) {
        uint4 v0 = *(const uint4*)&A [(size_t)(bm + ar0) * K + k0 + ak0];
        uint4 v1 = *(const uint4*)&A [(size_t)(bm + ar1) * K + k0 + ak1];
        uint4 v2 = *(const uint4*)&Al[(size_t)(bm + ar0) * K + k0 + ak0];
        uint4 v3 = *(const uint4*)&Al[(size_t)(bm + ar1) * K + k0 + ak1];
        float4 f[4];
        int bidx[4];
#pragma unroll
        for (int j = 0; j < 4; ++j) {
            const int c = tid + j * 256;          // 0..1023
            const int row = c >> 3, seg = c & 7;  // seg: 4-float group
            f[j] = *(const float4*)&Bf[(size_t)(bn + row) * K + k0 + seg * 4];
            bidx[j] = swz16(row, seg >> 1) + (seg & 1) * 4;
        }
        __syncthreads();
        *(uint4*)&As[0][w0] = v0;
        *(uint4*)&As[0][w1] = v1;
        *(uint4*)&As[1][w0] = v2;
        *(uint4*)&As[1][w1] = v3;
#pragma unroll
        for (int j = 0; j < 4; ++j) {
            const unsigned u0 = __float_as_uint(f[j].x), u1 = __float_as_uint(f[j].y);
            const unsigned u2 = __float_as_uint(f[j].z), u3 = __float_as_uint(f[j].w);
            uint2 hh, ll;
            hh.x = (u0 >> 16) | (u1 & 0xffff0000u);
            hh.y = (u2 >> 16) | (u3 & 0xffff0000u);
            const float r0 = f[j].x - __uint_as_float(u0 & 0xffff0000u);
            const float r1 = f[j].y - __uint_as_float(u1 & 0xffff0000u);
            const float r2 = f[j].z - __uint_as_float(u2 & 0xffff0000u);
            const float r3 = f[j].w - __uint_as_float(u3 & 0xffff0000u);
            ll.x = (__float_as_uint(r0) >> 16) | (__float_as_uint(r1) & 0xffff0000u);
            ll.y = (__float_as_uint(r2) >> 16) | (__float_as_uint(r3) & 0xffff0000u);
            *(uint2*)&Bs[0][bidx[j]] = hh;
            *(uint2*)&Bs[1][bidx[j]] = ll;
        }
        __syncthreads();
        bf16x8 ah[4], al[4], bh[4], bl[4];
#pragma unroll
        for (int m = 0; m < 4; ++m) {
            const int o = swz16(wr + m * 16 + r15, hi16);
            ah[m] = *(const bf16x8*)&As[0][o];
            al[m] = *(const bf16x8*)&As[1][o];
        }
#pragma unroll
        for (int n = 0; n < 4; ++n) {
            const int o = swz16(wc + n * 16 + r15, hi16);
            bh[n] = *(const bf16x8*)&Bs[0][o];
            bl[n] = *(const bf16x8*)&Bs[1][o];
        }
#pragma unroll
        for (int m = 0; m < 4; ++m)
#pragma unroll
            for (int n = 0; n < 4; ++n) {
                acc[m][n] = __builtin_amdgcn_mfma_f32_16x16x32_bf16(ah[m], bl[n], acc[m][n], 0, 0, 0);
                acc[m][n] = __builtin_amdgcn_mfma_f32_16x16x32_bf16(al[m], bh[n], acc[m][n], 0, 0, 0);
                acc[m][n] = __builtin_amdgcn_mfma_f32_16x16x32_bf16(ah[m], bh[n], acc[m][n], 0, 0, 0);
            }
    }
#pragma unroll
    for (int m = 0; m < 4; ++m)
#pragma unroll
        for (int n = 0; n < 4; ++n)
#pragma unroll
            for (int r = 0; r < 4; ++r)
                Cout[(size_t)(bm + wr + m * 16 + hi16 * 4 + r) * ldc
                     + bn + wc + n * 16 + r15] = acc[m][n][r];
}

// ---------------------------------------------------------------------------
// batched QK^T scores: Sc[bh][q][kpos] fp32. Qb [B,S,H,HDIM] split, Kb
// [B,S,KVH,HDIM] split. Causal/window block skip. Swizzled LDS.
// ---------------------------------------------------------------------------
__global__ __launch_bounds__(256) void qk_kernel(const u16* __restrict__ Qb, int qps,
                                                 const u16* __restrict__ Kb, int kps,
                                                 float* __restrict__ Sc,
                                                 int HDIM, int KVH, int win) {
    const int bm = blockIdx.y * 128;   // q tile
    const int bn = blockIdx.x * 128;   // k tile
    if (bn > bm + 127) return;                       // fully future
    if (win > 0 && bm - bn > win + 126) return;      // fully out of window
    const int bh = blockIdx.z;
    const int b = bh / cH, h = bh % cH;
    const int kh = h / (cH / KVH);

    __shared__ u16 As[2][128 * 32];
    __shared__ u16 Bs[2][128 * 32];
    const int tid = threadIdx.x;
    const int lane = tid & 63;
    const int w = tid >> 6;
    const int wr = (w >> 1) * 64, wc = (w & 1) * 64;
    const int r15 = lane & 15, hi16 = lane >> 4;

    const int lda = cH * HDIM, ldb = KVH * HDIM;
    const u16* Aq = Qb + ((size_t)b * cS * cH + h) * HDIM;
    const u16* Bk = Kb + ((size_t)b * cS * KVH + kh) * HDIM;

    f32x4 acc[4][4];
#pragma unroll
    for (int m = 0; m < 4; ++m)
#pragma unroll
        for (int n = 0; n < 4; ++n) acc[m][n] = (f32x4){0.f, 0.f, 0.f, 0.f};

    const int c0 = tid, c1 = tid + 256;
    const int ar0 = c0 >> 2, ak0 = (c0 & 3) * 8;
    const int ar1 = c1 >> 2, ak1 = (c1 & 3) * 8;
    const int w0 = swz16(ar0, c0 & 3), w1 = swz16(ar1, c1 & 3);

    for (int k0 = 0; k0 < HDIM; k0 += 32) {
        uint4 v0 = *(const uint4*)&Aq[(size_t)(bm + ar0) * lda + k0 + ak0];
        uint4 v1 = *(const uint4*)&Aq[(size_t)(bm + ar1) * lda + k0 + ak1];
        uint4 v2 = *(const uint4*)&Aq[(size_t)qps + (size_t)(bm + ar0) * lda + k0 + ak0];
        uint4 v3 = *(const uint4*)&Aq[(size_t)qps + (size_t)(bm + ar1) * lda + k0 + ak1];
        uint4 v4 = *(const uint4*)&Bk[(size_t)(bn + ar0) * ldb + k0 + ak0];
        uint4 v5 = *(const uint4*)&Bk[(size_t)(bn + ar1) * ldb + k0 + ak1];
        uint4 v6 = *(const uint4*)&Bk[(size_t)kps + (size_t)(bn + ar0) * ldb + k0 + ak0];
        uint4 v7 = *(const uint4*)&Bk[(size_t)kps + (size_t)(bn + ar1) * ldb + k0 + ak1];
        __syncthreads();
        *(uint4*)&As[0][w0] = v0;
        *(uint4*)&As[0][w1] = v1;
        *(uint4*)&As[1][w0] = v2;
        *(uint4*)&As[1][w1] = v3;
        *(uint4*)&Bs[0][w0] = v4;
        *(uint4*)&Bs[0][w1] = v5;
        *(uint4*)&Bs[1][w0] = v6;
        *(uint4*)&Bs[1][w1] = v7;
        __syncthreads();
        bf16x8 ah[4], al[4], bh4[4], bl4[4];
#pragma unroll
        for (int m = 0; m < 4; ++m) {
            const int o = swz16(wr + m * 16 + r15, hi16);
            ah[m] = *(const bf16x8*)&As[0][o];
            al[m] = *(const bf16x8*)&As[1][o];
        }
#pragma unroll
        for (int n = 0; n < 4; ++n) {
            const int o = swz16(wc + n * 16 + r15, hi16);
            bh4[n] = *(const bf16x8*)&Bs[0][o];
            bl4[n] = *(const bf16x8*)&Bs[1][o];
        }
#pragma unroll
        for (int m = 0; m < 4; ++m)
#pragma unroll
            for (int n = 0; n < 4; ++n) {
                acc[m][n] = __builtin_amdgcn_mfma_f32_16x16x32_bf16(ah[m], bl4[n], acc[m][n], 0, 0, 0);
                acc[m][n] = __builtin_amdgcn_mfma_f32_16x16x32_bf16(al[m], bh4[n], acc[m][n], 0, 0, 0);
                acc[m][n] = __builtin_amdgcn_mfma_f32_16x16x32_bf16(ah[m], bh4[n], acc[m][n], 0, 0, 0);
            }
    }
    float* Crow = Sc + (size_t)bh * cS * cS;
#pragma unroll
    for (int m = 0; m < 4; ++m)
#pragma unroll
        for (int n = 0; n < 4; ++n)
#pragma unroll
            for (int r = 0; r < 4; ++r)
                Crow[(size_t)(bm + wr + m * 16 + hi16 * 4 + r) * cS + bn + wc + n * 16 + r15]
                    = acc[m][n][r];
}

// ---------------------------------------------------------------------------
// row softmax over scores, in-place rewrite as split-bf16 P.
// ---------------------------------------------------------------------------
__global__ __launch_bounds__(256) void softmax_kernel(float* __restrict__ Sc,
                                                      const int* __restrict__ tlen,
                                                      int win) {
    const int q = blockIdx.x, bh = blockIdx.y, b = bh / cH;
    float* row = Sc + ((size_t)bh * cS + q) * cS;
    u16* rowh = (u16*)row;
    const int tid = threadIdx.x;
    const int tl = tlen[b];
    const int kmax = min(q, tl - 1);
    const int kmin = (win > 0) ? max(0, q - win + 1) : 0;

    float v[4];
    float m = -1e30f;
#pragma unroll
    for (int j = 0; j < 4; ++j) {
        const int k = tid + j * 256;
        const bool ok = (k >= kmin && k <= kmax);
        v[j] = ok ? row[k] : -1e30f;
        m = fmaxf(m, v[j]);
    }
    for (int o = 32; o >= 1; o >>= 1) m = fmaxf(m, __shfl_xor(m, o));
    __shared__ float rb[8];
    if ((tid & 63) == 0) rb[tid >> 6] = m;
    __syncthreads();
    m = fmaxf(fmaxf(rb[0], rb[1]), fmaxf(rb[2], rb[3]));

    float e[4];
    float s = 0.f;
#pragma unroll
    for (int j = 0; j < 4; ++j) {
        const int k = tid + j * 256;
        const bool ok = (k >= kmin && k <= kmax);
        e[j] = ok ? expf(v[j] - m) : 0.f;
        s += e[j];
    }
    for (int o = 32; o >= 1; o >>= 1) s += __shfl_xor(s, o);
    __shared__ float sb[4];
    if ((tid & 63) == 0) sb[tid >> 6] = s;
    __syncthreads();
    s = sb[0] + sb[1] + sb[2] + sb[3];
    const float inv = 1.f / s;
    __syncthreads();   // all fp32 reads complete before u16 overwrite
#pragma unroll
    for (int j = 0; j < 4; ++j) {
        const int k = tid + j * 256;
        u16 hh, ll;
        splitbf(e[j] * inv, hh, ll);
        rowh[k] = hh;
        rowh[1024 + k] = ll;
    }
}

// ---------------------------------------------------------------------------
// batched PV: O[b,q,h*HDIM+d] (split-bf16) = P[bh] @ V[b,kh]. Swizzled LDS.
// ---------------------------------------------------------------------------
__global__ __launch_bounds__(256) void pv_kernel(const u16* __restrict__ P,
                                                 const u16* __restrict__ Vt, int vps,
                                                 u16* __restrict__ O, int ops,
                                                 int HDIM, int KVH, int win) {
    const int bh = blockIdx.z;
    const int b = bh / cH, h = bh % cH;
    const int kh = h / (cH / KVH);
    const int bm = blockIdx.y * 128;   // q tile
    const int bn = blockIdx.x * 128;   // d tile

    __shared__ u16 As[2][128 * 32];
    __shared__ u16 Bs[2][128 * 32];
    const int tid = threadIdx.x;
    const int lane = tid & 63;
    const int w = tid >> 6;
    const int wr = (w >> 1) * 64, wc = (w & 1) * 64;
    const int r15 = lane & 15, hi16 = lane >> 4;

    const u16* Ap = P + (size_t)bh * cS * 2048;
    const u16* Bv = Vt + ((size_t)b * KVH + kh) * HDIM * cS;

    f32x4 acc[4][4];
#pragma unroll
    for (int m = 0; m < 4; ++m)
#pragma unroll
        for (int n = 0; n < 4; ++n) acc[m][n] = (f32x4){0.f, 0.f, 0.f, 0.f};

    const int c0 = tid, c1 = tid + 256;
    const int ar0 = c0 >> 2, ak0 = (c0 & 3) * 8;
    const int ar1 = c1 >> 2, ak1 = (c1 & 3) * 8;
    const int w0 = swz16(ar0, c0 & 3), w1 = swz16(ar1, c1 & 3);

    const int klo = (win > 0) ? (max(0, bm - win + 1) & ~31) : 0;
    const int khi = min(bm + 128, cS);

    for (int k0 = klo; k0 < khi; k0 += 32) {
        uint4 v0 = *(const uint4*)&Ap[(size_t)(bm + ar0) * 2048 + k0 + ak0];
        uint4 v1 = *(const uint4*)&Ap[(size_t)(bm + ar1) * 2048 + k0 + ak1];
        uint4 v2 = *(const uint4*)&Ap[(size_t)(bm + ar0) * 2048 + 1024 + k0 + ak0];
        uint4 v3 = *(const uint4*)&Ap[(size_t)(bm + ar1) * 2048 + 1024 + k0 + ak1];
        uint4 v4 = *(const uint4*)&Bv[(size_t)(bn + ar0) * cS + k0 + ak0];
        uint4 v5 = *(const uint4*)&Bv[(size_t)(bn + ar1) * cS + k0 + ak1];
        uint4 v6 = *(const uint4*)&Bv[(size_t)vps + (size_t)(bn + ar0) * cS + k0 + ak0];
        uint4 v7 = *(const uint4*)&Bv[(size_t)vps + (size_t)(bn + ar1) * cS + k0 + ak1];
        __syncthreads();
        *(uint4*)&As[0][w0] = v0;
        *(uint4*)&As[0][w1] = v1;
        *(uint4*)&As[1][w0] = v2;
        *(uint4*)&As[1][w1] = v3;
        *(uint4*)&Bs[0][w0] = v4;
        *(uint4*)&Bs[0][w1] = v5;
        *(uint4*)&Bs[1][w0] = v6;
        *(uint4*)&Bs[1][w1] = v7;
        __syncthreads();
        bf16x8 ah[4], al[4], bh4[4], bl4[4];
#pragma unroll
        for (int m = 0; m < 4; ++m) {
            const int o = swz16(wr + m * 16 + r15, hi16);
            ah[m] = *(const bf16x8*)&As[0][o];
            al[m] = *(const bf16x8*)&As[1][o];
        }
#pragma unroll
        for (int n = 0; n < 4; ++n) {
            const int o = swz16(wc + n * 16 + r15, hi16);
            bh4[n] = *(const bf16x8*)&Bs[0][o];
            bl4[n] = *(const bf16x8*)&Bs[1][o];
        }
#pragma unroll
        for (int m = 0; m < 4; ++m)
#pragma unroll
            for (int n = 0; n < 4; ++n) {
                acc[m][n] = __builtin_amdgcn_mfma_f32_16x16x32_bf16(ah[m], bl4[n], acc[m][n], 0, 0, 0);
                acc[m][n] = __builtin_amdgcn_mfma_f32_16x16x32_bf16(al[m], bh4[n], acc[m][n], 0, 0, 0);
                acc[m][n] = __builtin_amdgcn_mfma_f32_16x16x32_bf16(ah[m], bh4[n], acc[m][n], 0, 0, 0);
            }
    }
    const int ldo = cH * HDIM;
#pragma unroll
    for (int m = 0; m < 4; ++m)
#pragma unroll
        for (int n = 0; n < 4; ++n)
#pragma unroll
            for (int r = 0; r < 4; ++r) {
                const int q = bm + wr + m * 16 + hi16 * 4 + r;
                const int d = bn + wc + n * 16 + r15;
                const size_t idx = (size_t)(b * cS + q) * ldo + h * HDIM + d;
                u16 hh, ll;
                splitbf(acc[m][n][r], hh, ll);
                O[idx] = hh;
                O[(size_t)ops + idx] = ll;
            }
}

// ---------------------------------------------------------------------------
// gated FFN elementwise on split-bf16: out = gelu_tanh(g) * u  (4/thread)
// ---------------------------------------------------------------------------
__global__ void gelumul_kernel(const u16* __restrict__ g, const u16* __restrict__ u,
                               u16* __restrict__ out, int n, int ps) {
    const int i = blockIdx.x * blockDim.x + threadIdx.x;
    if (i * 4 >= n) return;
    const uint2 gh = *(const uint2*)&g[(size_t)i * 4];
    const uint2 gl = *(const uint2*)&g[(size_t)ps + (size_t)i * 4];
    const uint2 uh = *(const uint2*)&u[(size_t)i * 4];
    const uint2 ul = *(const uint2*)&u[(size_t)ps + (size_t)i * 4];
    auto gelu = [](float v) {
        const float t = tanhf(0.7978845608028654f * (v + 0.044715f * v * v * v));
        return 0.5f * v * (1.f + t);
    };
    float gv[4] = { bf2f((u16)(gh.x & 0xffff)) + bf2f((u16)(gl.x & 0xffff)),
                    bf2f((u16)(gh.x >> 16))    + bf2f((u16)(gl.x >> 16)),
                    bf2f((u16)(gh.y & 0xffff)) + bf2f((u16)(gl.y & 0xffff)),
                    bf2f((u16)(gh.y >> 16))    + bf2f((u16)(gl.y >> 16)) };
    float uv[4] = { bf2f((u16)(uh.x & 0xffff)) + bf2f((u16)(ul.x & 0xffff)),
                    bf2f((u16)(uh.x >> 16))    + bf2f((u16)(ul.x >> 16)),
                    bf2f((u16)(uh.y & 0xffff)) + bf2f((u16)(ul.y & 0xffff)),
                    bf2f((u16)(uh.y >> 16))    + bf2f((u16)(ul.y >> 16)) };
    u16 h[4], l[4];
#pragma unroll
    for (int j = 0; j < 4; ++j) splitbf(gelu(gv[j]) * uv[j], h[j], l[j]);
    uint2 oh, ol;
    oh.x = (unsigned)h[0] | ((unsigned)h[1] << 16);
    oh.y = (unsigned)h[2] | ((unsigned)h[3] << 16);
    ol.x = (unsigned)l[0] | ((unsigned)l[1] << 16);
    ol.y = (unsigned)l[2] | ((unsigned)l[3] << 16);
    *(uint2*)&out[(size_t)i * 4] = oh;
    *(uint2*)&out[(size_t)ps + (size_t)i * 4] = ol;
}

// ---------------------------------------------------------------------------
extern "C" void kernel_launch(void* const* d_in, const int* in_sizes, int n_in,
                              void* d_out, int out_size, void* d_ws, size_t ws_size,
                              hipStream_t stream) {
    (void)in_sizes; (void)n_in; (void)out_size; (void)ws_size;
    const int*   tokens = (const int*)  d_in[0];
    const int*   tlen   = (const int*)  d_in[1];
    const float* embed  = (const float*)d_in[2];
    const float* norm_w = (const float*)d_in[3];
    const float* s_wq   = (const float*)d_in[4];
    const float* s_wk   = (const float*)d_in[5];
    const float* s_wv   = (const float*)d_in[6];
    const float* s_wo   = (const float*)d_in[7];
    const float* s_qn   = (const float*)d_in[8];
    const float* s_kn   = (const float*)d_in[9];
    const float* s_wg   = (const float*)d_in[10];
    const float* s_wu   = (const float*)d_in[11];
    const float* s_wd   = (const float*)d_in[12];
    const float* s_ln1  = (const float*)d_in[13];
    const float* s_ln2  = (const float*)d_in[14];
    const float* s_ln3  = (const float*)d_in[15];
    const float* s_ln4  = (const float*)d_in[16];
    const float* s_scal = (const float*)d_in[17];
    const float* g_wq   = (const float*)d_in[18];
    const float* g_wk   = (const float*)d_in[19];
    const float* g_wo   = (const float*)d_in[20];
    const float* g_qn   = (const float*)d_in[21];
    const float* g_kn   = (const float*)d_in[22];
    const float* g_wg   = (const float*)d_in[23];
    const float* g_wu   = (const float*)d_in[24];
    const float* g_wd   = (const float*)d_in[25];
    const float* g_ln1  = (const float*)d_in[26];
    const float* g_ln2  = (const float*)d_in[27];
    const float* g_ln3  = (const float*)d_in[28];
    const float* g_ln4  = (const float*)d_in[29];
    const float* g_scal = (const float*)d_in[30];

    // workspace (160 MiB peak): same plan as round 4
    char* w8 = (char*)d_ws;
    float* x   = (float*)(w8);
    u16*   ab  = (u16*)(w8 + 16 * MB);
    u16*   Kb  = (u16*)(w8 + 16 * MB);
    float* r0  = (float*)(w8 + 32 * MB);
    float* scores = (float*)(w8 + 32 * MB);
    u16*   Pb  = (u16*)(w8 + 32 * MB);
    float* r1  = (float*)(w8 + 48 * MB);
    u16*   bb  = (u16*)(w8 + 64 * MB);
    float* t0f = (float*)(w8 + 96 * MB);
    u16*   Vt  = (u16*)(w8 + 96 * MB);
    u16*   t0b = (u16*)(w8 + 96 * MB);
    u16*   t1b = (u16*)(w8 + 128 * MB);

    constexpr int PS_AB = cM * cD;          // 4,194,304
    constexpr int CF    = 4096;             // FFN N-chunk

    auto tcast = [&](const float* in, u16* outp, int K, int N, int ldin, int ps) {
        tcast_kernel<<<dim3(N / 32, K / 32), 256, 0, stream>>>(in, outp, K, N, ldin, ps);
    };
    auto gemmF = [&](const u16* A, const u16* Bt, float* C, int M, int N, int K,
                     int ldc, int aps, int bps, bool accum) {
        if (accum)
            gemm_split<false, true><<<dim3(N / 128, M / 128), 256, 0, stream>>>(
                A, Bt, C, M, N, K, ldc, aps, bps, 0);
        else
            gemm_split<false, false><<<dim3(N / 128, M / 128), 256, 0, stream>>>(
                A, Bt, C, M, N, K, ldc, aps, bps, 0);
    };
    auto gemmB = [&](const u16* A, const u16* Bt, u16* C, int M, int N, int K,
                     int ldc, int aps, int bps, int cps) {
        gemm_split<true, false><<<dim3(N / 128, M / 128), 256, 0, stream>>>(
            A, Bt, C, M, N, K, ldc, aps, bps, cps);
    };

    // attention via MFMA: Q fp32 in t0f, K fp32 in r0, V fp32 in r1
    auto attention = [&](int HDIM, int KVH, int win) {
        const int qn = cM * cH * HDIM;
        const int kn = cM * KVH * HDIM;
        cast_kernel<<<(qn / 4 + 255) / 256, 256, 0, stream>>>(t0f, t1b, qn, qn);   // Qb
        cast_kernel<<<(kn / 4 + 255) / 256, 256, 0, stream>>>(r0, Kb, kn, kn);     // Kb
        vtrans_kernel<<<dim3(HDIM / 32, cS / 32, cB * KVH), 256, 0, stream>>>(
            r1, Vt, HDIM, KVH, kn);                                                // Vt
        qk_kernel<<<dim3(cS / 128, cS / 128, cB * cH), 256, 0, stream>>>(
            t1b, qn, Kb, kn, scores, HDIM, KVH, win);
        softmax_kernel<<<dim3(cS, cB * cH), 256, 0, stream>>>(scores, tlen, win);
        pv_kernel<<<dim3(HDIM / 128, cS / 128, cB * cH), 256, 0, stream>>>(
            Pb, Vt, kn, t1b, qn, HDIM, KVH, win);                                  // O -> t1b
    };

    embed_kernel<<<cM, 256, 0, stream>>>(tokens, embed, x);

    // ================= block 1: sliding-window =================
    rms_bf16_kernel<<<cM, 256, 0, stream>>>(x, s_ln1, ab, cD, PS_AB);
    tcast(s_wq, bb, cD, cH * cHD, cH * cHD, cD * cH * cHD);
    gemmF(ab, bb, t0f, cM, cH * cHD, cD, cH * cHD, PS_AB, cD * cH * cHD, false);
    tcast(s_wk, bb, cD, cKV * cHD, cKV * cHD, cD * cKV * cHD);
    gemmF(ab, bb, r0, cM, cKV * cHD, cD, cKV * cHD, PS_AB, cD * cKV * cHD, false);
    tcast(s_wv, bb, cD, cKV * cHD, cKV * cHD, cD * cKV * cHD);
    gemmF(ab, bb, r1, cM, cKV * cHD, cD, cKV * cHD, PS_AB, cD * cKV * cHD, false);
    rms_kernel<<<cM * cKV, 256, 0, stream>>>(r1, nullptr, r1, cHD);     // xv = rms_ns(h@wv)
    rms_kernel<<<cM * cH, 256, 0, stream>>>(t0f, s_qn, t0f, cHD);
    rms_kernel<<<cM * cKV, 256, 0, stream>>>(r0, s_kn, r0, cHD);
    rope_kernel<<<cM * cH, 128, 0, stream>>>(t0f, cH, cHD, cHD, 10000.f);
    rope_kernel<<<cM * cKV, 128, 0, stream>>>(r0, cKV, cHD, cHD, 10000.f);
    attention(cHD, cKV, cWIN);
    tcast(s_wo, bb, cH * cHD, cD, cD, cH * cHD * cD);
    gemmF(t1b, bb, r0, cM, cD, cH * cHD, cD, cM * cH * cHD, cH * cHD * cD, false);
    rms_add_kernel<<<cM, 256, 0, stream>>>(x, r0, s_ln2, nullptr, x, cD);
    rms_bf16_kernel<<<cM, 256, 0, stream>>>(x, s_ln3, ab, cD, PS_AB);
    for (int c = 0; c < cF / CF; ++c) {
        tcast(s_wg + (size_t)c * CF, bb, cD, CF, cF, cD * CF);
        gemmB(ab, bb, t0b, cM, CF, cD, CF, PS_AB, cD * CF, cM * CF);
        tcast(s_wu + (size_t)c * CF, bb, cD, CF, cF, cD * CF);
        gemmB(ab, bb, t1b, cM, CF, cD, CF, PS_AB, cD * CF, cM * CF);
        gelumul_kernel<<<(cM * CF / 4 + 255) / 256, 256, 0, stream>>>(t0b, t1b, t0b,
                                                                     cM * CF, cM * CF);
        tcast(s_wd + (size_t)c * CF * cD, bb, CF, cD, cD, CF * cD);
        gemmF(t0b, bb, r0, cM, cD, CF, cD, cM * CF, CF * cD, c > 0);
    }
    rms_add_kernel<<<cM, 256, 0, stream>>>(x, r0, s_ln4, s_scal, x, cD);

    // ================= block 2: global =================
    rms_bf16_kernel<<<cM, 256, 0, stream>>>(x, g_ln1, ab, cD, PS_AB);
    tcast(g_wq, bb, cD, cH * cGHD, cH * cGHD, cD * cH * cGHD);
    gemmF(ab, bb, t0f, cM, cH * cGHD, cD, cH * cGHD, PS_AB, cD * cH * cGHD, false);
    tcast(g_wk, bb, cD, cGKV * cGHD, cGKV * cGHD, cD * cGKV * cGHD);
    gemmF(ab, bb, r0, cM, cGKV * cGHD, cD, cGKV * cGHD, PS_AB, cD * cGKV * cGHD, false);
    rms_kernel<<<cM * cGKV, 256, 0, stream>>>(r0, nullptr, r1, cGHD);   // xv = rms_ns(raw xk)
    rms_kernel<<<cM * cH, 256, 0, stream>>>(t0f, g_qn, t0f, cGHD);
    rms_kernel<<<cM * cGKV, 256, 0, stream>>>(r0, g_kn, r0, cGHD);
    rope_kernel<<<cM * cH, 64, 0, stream>>>(t0f, cH, cGHD, cROT, 1000000.f);
    rope_kernel<<<cM * cGKV, 64, 0, stream>>>(r0, cGKV, cGHD, cROT, 1000000.f);
    attention(cGHD, cGKV, 0);
    tcast(g_wo, bb, cH * cGHD, cD, cD, cH * cGHD * cD);
    gemmF(t1b, bb, r0, cM, cD, cH * cGHD, cD, cM * cH * cGHD, cH * cGHD * cD, false);
    rms_add_kernel<<<cM, 256, 0, stream>>>(x, r0, g_ln2, nullptr, x, cD);
    rms_bf16_kernel<<<cM, 256, 0, stream>>>(x, g_ln3, ab, cD, PS_AB);
    for (int c = 0; c < cF / CF; ++c) {
        tcast(g_wg + (size_t)c * CF, bb, cD, CF, cF, cD * CF);
        gemmB(ab, bb, t0b, cM, CF, cD, CF, PS_AB, cD * CF, cM * CF);
        tcast(g_wu + (size_t)c * CF, bb, cD, CF, cF, cD * CF);
        gemmB(ab, bb, t1b, cM, CF, cD, CF, PS_AB, cD * CF, cM * CF);
        gelumul_kernel<<<(cM * CF / 4 + 255) / 256, 256, 0, stream>>>(t0b, t1b, t0b,
                                                                     cM * CF, cM * CF);
        tcast(g_wd + (size_t)c * CF * cD, bb, CF, cD, cD, CF * cD);
        gemmF(t0b, bb, r0, cM, cD, CF, cD, cM * CF, CF * cD, c > 0);
    }
    rms_add_kernel<<<cM, 256, 0, stream>>>(x, r0, g_ln4, g_scal, x, cD);

    // ================= final norm + logits (single unchunked GEMM) =========
    rms_bf16_kernel<<<cM, 256, 0, stream>>>(x, norm_w, ab, cD, PS_AB);
    gemm_absplit_bfp32<<<dim3(cV / 128, cM / 128), 256, 0, stream>>>(
        ab, PS_AB, embed, (float*)d_out, cM, cV, cD, cV);
}